// Round 1
// baseline (1205.211 us; speedup 1.0000x reference)
//
#include <hip/hip_runtime.h>
#include <hip/hip_bf16.h>
#include <math.h>

#define DIM 256
#define NHEAD 4
#define HD 64

__device__ __forceinline__ float sigmoidf_(float x) { return 1.0f / (1.0f + __expf(-x)); }
__device__ __forceinline__ float geluf_(float x) {
    return 0.5f * x * (1.0f + erff(x * 0.70710678118654752440f));
}
__device__ __forceinline__ float wave_sum64(float v) {
    v += __shfl_xor(v, 32); v += __shfl_xor(v, 16); v += __shfl_xor(v, 8);
    v += __shfl_xor(v, 4);  v += __shfl_xor(v, 2);  v += __shfl_xor(v, 1);
    return v;
}

// ---------------------------------------------------------------------------
// Generic fp32 GEMM: C[N,Kout] = epilogue( act(A[N,Kin]) @ W^T + bias )
// W selected per 256-col chunk (lets one launch fuse k|q|v projections).
// OUT_MODE 0: C = acc+bias
// OUT_MODE 1: C = sig(skip)*(acc+bias) + (1-sig)*xres     (HGT out)
// OUT_MODE 2: scores[r] += relu(acc+bias) . w2  (+b2 once) (scoring head)
// IN_GELU 1: exact gelu applied to A elements on load.
// ---------------------------------------------------------------------------
template<int IN_GELU, int OUT_MODE>
__launch_bounds__(256)
__global__ void gemm_kernel(const float* __restrict__ A, int lda,
                            const float* __restrict__ W0, const float* __restrict__ W1,
                            const float* __restrict__ W2, int ldw,
                            const float* __restrict__ B0, const float* __restrict__ B1,
                            const float* __restrict__ B2,
                            float* __restrict__ C, int ldc, int Kin,
                            const float* __restrict__ xres,
                            const float* __restrict__ skipv,
                            float* __restrict__ scores,
                            const float* __restrict__ w2v,
                            const float* __restrict__ b2v)
{
    __shared__ float As[16][68];
    __shared__ float Ws[16][68];
    const int t = threadIdx.x;
    const int r0 = blockIdx.y * 64;
    const int c0 = blockIdx.x * 64;
    const int widx = c0 >> 8;
    const float* W  = (widx == 0) ? W0 : (widx == 1 ? W1 : W2);
    const float* Bv = (widx == 0) ? B0 : (widx == 1 ? B1 : B2);
    const int cw = c0 & 255;

    const int lrow = t >> 2;          // 0..63
    const int lk   = (t & 3) << 2;    // 0,4,8,12
    const int ty = t >> 4, tx = t & 15;

    const float* Aptr = A + (size_t)(r0 + lrow) * lda + lk;
    const float* Wptr = W + (size_t)(cw + lrow) * ldw + lk;

    float acc[4][4] = {};
    for (int k0 = 0; k0 < Kin; k0 += 16) {
        float4 av = *reinterpret_cast<const float4*>(Aptr + k0);
        float4 wv = *reinterpret_cast<const float4*>(Wptr + k0);
        if (IN_GELU) {
            av.x = geluf_(av.x); av.y = geluf_(av.y);
            av.z = geluf_(av.z); av.w = geluf_(av.w);
        }
        As[lk + 0][lrow] = av.x; As[lk + 1][lrow] = av.y;
        As[lk + 2][lrow] = av.z; As[lk + 3][lrow] = av.w;
        Ws[lk + 0][lrow] = wv.x; Ws[lk + 1][lrow] = wv.y;
        Ws[lk + 2][lrow] = wv.z; Ws[lk + 3][lrow] = wv.w;
        __syncthreads();
#pragma unroll
        for (int k = 0; k < 16; ++k) {
            const float4 a = *reinterpret_cast<const float4*>(&As[k][ty << 2]);
            const float4 b = *reinterpret_cast<const float4*>(&Ws[k][tx << 2]);
            const float ar[4] = {a.x, a.y, a.z, a.w};
            const float br[4] = {b.x, b.y, b.z, b.w};
#pragma unroll
            for (int i = 0; i < 4; ++i)
#pragma unroll
                for (int j = 0; j < 4; ++j)
                    acc[i][j] = fmaf(ar[i], br[j], acc[i][j]);
        }
        __syncthreads();
    }

    float bias[4];
#pragma unroll
    for (int j = 0; j < 4; ++j) bias[j] = Bv[cw + (tx << 2) + j];

    if (OUT_MODE == 0) {
#pragma unroll
        for (int i = 0; i < 4; ++i) {
            float4 st;
            st.x = acc[i][0] + bias[0]; st.y = acc[i][1] + bias[1];
            st.z = acc[i][2] + bias[2]; st.w = acc[i][3] + bias[3];
            *reinterpret_cast<float4*>(&C[(size_t)(r0 + (ty << 2) + i) * ldc + c0 + (tx << 2)]) = st;
        }
    } else if (OUT_MODE == 1) {
        const float sg = sigmoidf_(skipv[0]);
#pragma unroll
        for (int i = 0; i < 4; ++i) {
            const int r = r0 + (ty << 2) + i;
            const float4 xv = *reinterpret_cast<const float4*>(&xres[(size_t)r * ldc + c0 + (tx << 2)]);
            float4 st;
            st.x = sg * (acc[i][0] + bias[0]) + (1.f - sg) * xv.x;
            st.y = sg * (acc[i][1] + bias[1]) + (1.f - sg) * xv.y;
            st.z = sg * (acc[i][2] + bias[2]) + (1.f - sg) * xv.z;
            st.w = sg * (acc[i][3] + bias[3]) + (1.f - sg) * xv.w;
            *reinterpret_cast<float4*>(&C[(size_t)r * ldc + c0 + (tx << 2)]) = st;
        }
    } else {
        float wv[4];
#pragma unroll
        for (int j = 0; j < 4; ++j) wv[j] = w2v[c0 + (tx << 2) + j];
#pragma unroll
        for (int i = 0; i < 4; ++i) {
            float p = 0.f;
#pragma unroll
            for (int j = 0; j < 4; ++j)
                p = fmaf(fmaxf(acc[i][j] + bias[j], 0.f), wv[j], p);
            if (c0 == 0 && tx == 0) p += b2v[0];
            atomicAdd(&scores[r0 + (ty << 2) + i], p);
        }
    }
}

// ---------------------------------------------------------------------------
// kt[n, h*64+e] = sum_d kin[n, h*64+d] * arel[h, d, e]      (per-head 64x64)
// ---------------------------------------------------------------------------
__launch_bounds__(256)
__global__ void rel_transform_kernel(const float* __restrict__ kin, int ldin,
                                     const float* __restrict__ arel,
                                     float* __restrict__ kout)
{
    __shared__ float Al[64][68];   // [d][e]
    __shared__ float Kl[64][65];   // [r][d]
    const int t = threadIdx.x;
    const int r0 = blockIdx.x * 64;
    const int h = blockIdx.y;
    const float* ah = arel + h * 4096;
    for (int i = t; i < 1024; i += 256) {
        const int rr = i >> 4, c4 = (i & 15) << 2;
        const float4 av = *reinterpret_cast<const float4*>(&ah[rr * 64 + c4]);
        *reinterpret_cast<float4*>(&Al[rr][c4]) = av;
        const float4 kv = *reinterpret_cast<const float4*>(&kin[(size_t)(r0 + rr) * ldin + h * 64 + c4]);
        Kl[rr][c4 + 0] = kv.x; Kl[rr][c4 + 1] = kv.y;
        Kl[rr][c4 + 2] = kv.z; Kl[rr][c4 + 3] = kv.w;
    }
    __syncthreads();
    const int r  = t & 63;
    const int e0 = (t >> 6) << 4;   // 0,16,32,48
    float acc[16] = {};
    for (int d = 0; d < 64; ++d) {
        const float kv = Kl[r][d];
#pragma unroll
        for (int u4 = 0; u4 < 4; ++u4) {
            const float4 a = *reinterpret_cast<const float4*>(&Al[d][e0 + (u4 << 2)]);
            acc[u4 * 4 + 0] = fmaf(kv, a.x, acc[u4 * 4 + 0]);
            acc[u4 * 4 + 1] = fmaf(kv, a.y, acc[u4 * 4 + 1]);
            acc[u4 * 4 + 2] = fmaf(kv, a.z, acc[u4 * 4 + 2]);
            acc[u4 * 4 + 3] = fmaf(kv, a.w, acc[u4 * 4 + 3]);
        }
    }
#pragma unroll
    for (int u4 = 0; u4 < 4; ++u4) {
        float4 st = {acc[u4 * 4 + 0], acc[u4 * 4 + 1], acc[u4 * 4 + 2], acc[u4 * 4 + 3]};
        *reinterpret_cast<float4*>(&kout[(size_t)(r0 + r) * 256 + h * 64 + e0 + (u4 << 2)]) = st;
    }
}

// --------------------------- CSR build -------------------------------------
__global__ void edge_count_kernel(const int* __restrict__ dst, int* __restrict__ cnt, int E)
{
    const int i = blockIdx.x * 256 + threadIdx.x;
    if (i < E) atomicAdd(&cnt[dst[i]], 1);
}

// 4096-element exclusive scan: 1 block, 1024 threads x int4
__launch_bounds__(1024)
__global__ void scan_kernel(const int* __restrict__ cnt, int* __restrict__ indptr,
                            int* __restrict__ cursor)
{
    __shared__ int sh[1024];
    const int t = threadIdx.x;
    const int4 v = *reinterpret_cast<const int4*>(&cnt[t << 2]);
    const int sum = v.x + v.y + v.z + v.w;
    sh[t] = sum;
    __syncthreads();
    for (int off = 1; off < 1024; off <<= 1) {
        int x = 0;
        if (t >= off) x = sh[t - off];
        __syncthreads();
        if (t >= off) sh[t] += x;
        __syncthreads();
    }
    int run = sh[t] - sum;   // exclusive prefix of this thread's group
    const int base = t << 2;
    if (t == 0) indptr[0] = 0;
    cursor[base + 0] = run; run += v.x; indptr[base + 1] = run;
    cursor[base + 1] = run; run += v.y; indptr[base + 2] = run;
    cursor[base + 2] = run; run += v.z; indptr[base + 3] = run;
    cursor[base + 3] = run; run += v.w; indptr[base + 4] = run;
}

__global__ void edge_scatter_kernel(const int* __restrict__ src, const int* __restrict__ dst,
                                    int* __restrict__ cursor, int* __restrict__ ssrc, int E)
{
    const int i = blockIdx.x * 256 + threadIdx.x;
    if (i < E) {
        const int p = atomicAdd(&cursor[dst[i]], 1);
        ssrc[p] = src[i];
    }
}

// ---------------------------------------------------------------------------
// HGT edge softmax-aggregate: one wave per (dst node, head), lane = d.
// ---------------------------------------------------------------------------
__launch_bounds__(256)
__global__ void hgt_attn_kernel(const float* __restrict__ qdst,   // base already at q cols, ld=768
                                const float* __restrict__ kt,
                                const float* __restrict__ vt,
                                const float* __restrict__ prel,
                                const int* __restrict__ indptr,
                                const int* __restrict__ ssrc,
                                float* __restrict__ agg)
{
    const int gw = (blockIdx.x * 256 + threadIdx.x) >> 6;
    const int lane = threadIdx.x & 63;
    const int n = gw >> 2;
    const int h = gw & 3;
    const float q = qdst[(size_t)n * 768 + h * 64 + lane];
    const float ps = prel[h] * 0.125f;                 // p_rel / sqrt(64)
    const int e0 = indptr[n], e1 = indptr[n + 1];
    float m = -1e30f, s = 0.f, acc = 0.f;
    for (int e = e0; e < e1; ++e) {
        const int sr = ssrc[e];
        float d = q * kt[(size_t)sr * 256 + h * 64 + lane];
        d = wave_sum64(d);
        const float logit = d * ps;
        const float mn = fmaxf(m, logit);
        const float f = __expf(m - mn);
        const float p = __expf(logit - mn);
        s = s * f + p;
        acc = acc * f + p * vt[(size_t)sr * 256 + h * 64 + lane];
        m = mn;
    }
    agg[(size_t)n * 256 + h * 64 + lane] = acc / (s + 1e-16f);
}

// ---------------------------------------------------------------------------
// MHA flash attention, fp32. Block: (head, 32 q-rows); 64-key tiles in LDS.
// qkv layout [N,768]: q|k|v each 256 cols, head h at +h*64.
// ---------------------------------------------------------------------------
__launch_bounds__(256)
__global__ void mha_flash_kernel(const float* __restrict__ qkv, float* __restrict__ outp, int N)
{
    __shared__ float Qs[64][36];   // [d][r]
    __shared__ float Ks[64][68];   // [d][c]
    __shared__ float Vs[64][68];   // [c][d]
    __shared__ float Ps[64][36];   // [c][r]  (S^T, then P^T)
    __shared__ float mrow[32], lrow[32], frow[32];
    const int t = threadIdx.x;
    const int r0 = blockIdx.x * 32;
    const int h  = blockIdx.y;
    const int ty = t >> 5;        // 0..7  -> rows ty*4..+3
    const int tx = t & 31;        // 0..31 -> cols tx*2..+1

    for (int i = t; i < 512; i += 256) {
        const int r = i >> 4, d4 = (i & 15) << 2;
        const float4 v = *reinterpret_cast<const float4*>(&qkv[(size_t)(r0 + r) * 768 + h * 64 + d4]);
        Qs[d4 + 0][r] = v.x; Qs[d4 + 1][r] = v.y; Qs[d4 + 2][r] = v.z; Qs[d4 + 3][r] = v.w;
    }
    if (t < 32) { mrow[t] = -1e30f; lrow[t] = 0.f; }
    float o[4][2] = {};
    __syncthreads();

    for (int kb = 0; kb < N; kb += 64) {
        for (int i = t; i < 1024; i += 256) {
            const int c = i >> 4, d4 = (i & 15) << 2;
            const float4 kv = *reinterpret_cast<const float4*>(&qkv[(size_t)(kb + c) * 768 + 256 + h * 64 + d4]);
            Ks[d4 + 0][c] = kv.x; Ks[d4 + 1][c] = kv.y; Ks[d4 + 2][c] = kv.z; Ks[d4 + 3][c] = kv.w;
            const float4 vv = *reinterpret_cast<const float4*>(&qkv[(size_t)(kb + c) * 768 + 512 + h * 64 + d4]);
            *reinterpret_cast<float4*>(&Vs[c][d4]) = vv;
        }
        __syncthreads();

        float s[4][2] = {};
#pragma unroll 8
        for (int d = 0; d < 64; ++d) {
            const float4 a = *reinterpret_cast<const float4*>(&Qs[d][ty << 2]);
            const float2 b = *reinterpret_cast<const float2*>(&Ks[d][tx << 1]);
            s[0][0] = fmaf(a.x, b.x, s[0][0]); s[0][1] = fmaf(a.x, b.y, s[0][1]);
            s[1][0] = fmaf(a.y, b.x, s[1][0]); s[1][1] = fmaf(a.y, b.y, s[1][1]);
            s[2][0] = fmaf(a.z, b.x, s[2][0]); s[2][1] = fmaf(a.z, b.y, s[2][1]);
            s[3][0] = fmaf(a.w, b.x, s[3][0]); s[3][1] = fmaf(a.w, b.y, s[3][1]);
        }
#pragma unroll
        for (int i = 0; i < 4; ++i) {
            Ps[(tx << 1) + 0][(ty << 2) + i] = s[i][0] * 0.125f;
            Ps[(tx << 1) + 1][(ty << 2) + i] = s[i][1] * 0.125f;
        }
        __syncthreads();

        if (t < 32) {
            const int r = t;
            const float m0 = mrow[r];
            float mt = m0;
            for (int c = 0; c < 64; ++c) mt = fmaxf(mt, Ps[c][r]);
            const float f = __expf(m0 - mt);
            float l = lrow[r] * f;
            for (int c = 0; c < 64; ++c) {
                const float p = __expf(Ps[c][r] - mt);
                Ps[c][r] = p;
                l += p;
            }
            mrow[r] = mt; lrow[r] = l; frow[r] = f;
        }
        __syncthreads();

        const float fr[4] = {frow[(ty << 2) + 0], frow[(ty << 2) + 1],
                             frow[(ty << 2) + 2], frow[(ty << 2) + 3]};
#pragma unroll
        for (int i = 0; i < 4; ++i) { o[i][0] *= fr[i]; o[i][1] *= fr[i]; }
#pragma unroll 8
        for (int c = 0; c < 64; ++c) {
            const float4 a = *reinterpret_cast<const float4*>(&Ps[c][ty << 2]);
            const float2 b = *reinterpret_cast<const float2*>(&Vs[c][tx << 1]);
            o[0][0] = fmaf(a.x, b.x, o[0][0]); o[0][1] = fmaf(a.x, b.y, o[0][1]);
            o[1][0] = fmaf(a.y, b.x, o[1][0]); o[1][1] = fmaf(a.y, b.y, o[1][1]);
            o[2][0] = fmaf(a.z, b.x, o[2][0]); o[2][1] = fmaf(a.z, b.y, o[2][1]);
            o[3][0] = fmaf(a.w, b.x, o[3][0]); o[3][1] = fmaf(a.w, b.y, o[3][1]);
        }
        __syncthreads();
    }
#pragma unroll
    for (int i = 0; i < 4; ++i) {
        const float li = 1.f / lrow[(ty << 2) + i];
        float2 st = {o[i][0] * li, o[i][1] * li};
        *reinterpret_cast<float2*>(&outp[(size_t)(r0 + (ty << 2) + i) * 256 + h * 64 + (tx << 1)]) = st;
    }
}

// ---------------------------------------------------------------------------
// h_ent = LN(0.9*h_ent + 0.1*h_glob); rel = sigmoid(h_ent . q). Wave per row.
// ---------------------------------------------------------------------------
__launch_bounds__(256)
__global__ void mix_ln_rel_kernel(float* __restrict__ he, const float* __restrict__ hg,
                                  const float* __restrict__ g, const float* __restrict__ b,
                                  const float* __restrict__ q, float* __restrict__ rel)
{
    const int row = (blockIdx.x * 256 + threadIdx.x) >> 6;
    const int lane = threadIdx.x & 63;
    const float4 a = *reinterpret_cast<const float4*>(&he[(size_t)row * 256 + (lane << 2)]);
    const float4 c = *reinterpret_cast<const float4*>(&hg[(size_t)row * 256 + (lane << 2)]);
    float4 v;
    v.x = 0.9f * a.x + 0.1f * c.x; v.y = 0.9f * a.y + 0.1f * c.y;
    v.z = 0.9f * a.z + 0.1f * c.z; v.w = 0.9f * a.w + 0.1f * c.w;
    const float mean = wave_sum64(v.x + v.y + v.z + v.w) * (1.f / 256.f);
    float4 d = {v.x - mean, v.y - mean, v.z - mean, v.w - mean};
    const float var = wave_sum64(d.x * d.x + d.y * d.y + d.z * d.z + d.w * d.w) * (1.f / 256.f);
    const float rs = rsqrtf(var + 1e-5f);
    const float4 gg = *reinterpret_cast<const float4*>(&g[lane << 2]);
    const float4 bb = *reinterpret_cast<const float4*>(&b[lane << 2]);
    float4 y = {d.x * rs * gg.x + bb.x, d.y * rs * gg.y + bb.y,
                d.z * rs * gg.z + bb.z, d.w * rs * gg.w + bb.w};
    *reinterpret_cast<float4*>(&he[(size_t)row * 256 + (lane << 2)]) = y;
    const float4 qq = *reinterpret_cast<const float4*>(&q[lane << 2]);
    const float dq = wave_sum64(y.x * qq.x + y.y * qq.y + y.z * qq.z + y.w * qq.w);
    if (lane == 0) rel[row] = sigmoidf_(dq);
}

// ctx[p] = sum_{e in seg(p)} h_ent[src]*rel[src]. Wave per (p, quarter).
__launch_bounds__(256)
__global__ void ctx_gather_kernel(const float* __restrict__ he, const float* __restrict__ rel,
                                  const int* __restrict__ indptr, const int* __restrict__ ssrc,
                                  float* __restrict__ ctx)
{
    const int gw = (blockIdx.x * 256 + threadIdx.x) >> 6;
    const int lane = threadIdx.x & 63;
    const int p = gw >> 2, qt = gw & 3;
    const int e0 = indptr[p], e1 = indptr[p + 1];
    float acc = 0.f;
    for (int e = e0; e < e1; ++e) {
        const int sr = ssrc[e];
        acc = fmaf(he[(size_t)sr * 256 + qt * 64 + lane], rel[sr], acc);
    }
    ctx[(size_t)p * 256 + qt * 64 + lane] = acc;
}

// h_psg = LN(h_psg + ctx). Wave per row.
__launch_bounds__(256)
__global__ void psg_ln_kernel(float* __restrict__ hp, const float* __restrict__ ctx,
                              const float* __restrict__ g, const float* __restrict__ b)
{
    const int row = (blockIdx.x * 256 + threadIdx.x) >> 6;
    const int lane = threadIdx.x & 63;
    const float4 a = *reinterpret_cast<const float4*>(&hp[(size_t)row * 256 + (lane << 2)]);
    const float4 c = *reinterpret_cast<const float4*>(&ctx[(size_t)row * 256 + (lane << 2)]);
    float4 v = {a.x + c.x, a.y + c.y, a.z + c.z, a.w + c.w};
    const float mean = wave_sum64(v.x + v.y + v.z + v.w) * (1.f / 256.f);
    float4 d = {v.x - mean, v.y - mean, v.z - mean, v.w - mean};
    const float var = wave_sum64(d.x * d.x + d.y * d.y + d.z * d.z + d.w * d.w) * (1.f / 256.f);
    const float rs = rsqrtf(var + 1e-5f);
    const float4 gg = *reinterpret_cast<const float4*>(&g[lane << 2]);
    const float4 bb = *reinterpret_cast<const float4*>(&b[lane << 2]);
    float4 y = {d.x * rs * gg.x + bb.x, d.y * rs * gg.y + bb.y,
                d.z * rs * gg.z + bb.z, d.w * rs * gg.w + bb.w};
    *reinterpret_cast<float4*>(&hp[(size_t)row * 256 + (lane << 2)]) = y;
}

// qterm[j] = b1[j] + w1[j, 256:512] . q   (query half of the scoring matmul)
__global__ void qterm_kernel(const float* __restrict__ w1, const float* __restrict__ b1,
                             const float* __restrict__ q, float* __restrict__ qterm)
{
    __shared__ float qs[256];
    const int t = threadIdx.x;
    qs[t] = q[t];
    __syncthreads();
    float s = b1[t];
    for (int k = 0; k < 256; ++k) s = fmaf(w1[(size_t)t * 512 + 256 + k], qs[k], s);
    qterm[t] = s;
}

// ---------------------------------------------------------------------------
extern "C" void kernel_launch(void* const* d_in, const int* in_sizes, int n_in,
                              void* d_out, int out_size, void* d_ws, size_t ws_size,
                              hipStream_t stream)
{
    const float* x_ent = (const float*)d_in[0];
    const float* x_psg = (const float*)d_in[1];
    const float* q_emb = (const float*)d_in[2];
    const float* Wk_e = (const float*)d_in[3];  const float* bk_e = (const float*)d_in[4];
    const float* Wq_e = (const float*)d_in[5];  const float* bq_e = (const float*)d_in[6];
    const float* Wv_e = (const float*)d_in[7];  const float* bv_e = (const float*)d_in[8];
    const float* Wo_e = (const float*)d_in[9];  const float* bo_e = (const float*)d_in[10];
    const float* sk_e = (const float*)d_in[11];
    const float* Wk_p = (const float*)d_in[12]; const float* bk_p = (const float*)d_in[13];
    const float* Wq_p = (const float*)d_in[14]; const float* bq_p = (const float*)d_in[15];
    const float* Wv_p = (const float*)d_in[16]; const float* bv_p = (const float*)d_in[17];
    const float* Wo_p = (const float*)d_in[18]; const float* bo_p = (const float*)d_in[19];
    const float* sk_p = (const float*)d_in[20];
    const float* a_e2p = (const float*)d_in[21];
    const float* m_e2p = (const float*)d_in[22];
    const float* p_e2p = (const float*)d_in[23];
    const float* a_p2e = (const float*)d_in[24];
    const float* m_p2e = (const float*)d_in[25];
    const float* p_p2e = (const float*)d_in[26];
    const float* Wmi = (const float*)d_in[27];  const float* bmi = (const float*)d_in[28];
    const float* Wmo = (const float*)d_in[29];  const float* bmo = (const float*)d_in[30];
    const float* lng_e = (const float*)d_in[31]; const float* lnb_e = (const float*)d_in[32];
    const float* lng_p = (const float*)d_in[33]; const float* lnb_p = (const float*)d_in[34];
    const float* w1 = (const float*)d_in[35];   const float* b1 = (const float*)d_in[36];
    const float* w2 = (const float*)d_in[37];   const float* b2 = (const float*)d_in[38];
    const int* e2p_src = (const int*)d_in[39];
    const int* e2p_dst = (const int*)d_in[40];
    const int* p2e_src = (const int*)d_in[41];
    const int* p2e_dst = (const int*)d_in[42];

    const int NE = in_sizes[0] / DIM;
    const int NP = in_sizes[1] / DIM;
    const int E  = in_sizes[39];
    float* scores = (float*)d_out;

    char* wp = (char*)d_ws;
    auto alloc = [&](size_t bytes) -> void* {
        void* r = (void*)wp;
        wp += (bytes + 255) & ~(size_t)255;
        return r;
    };
    float* kqv_e = (float*)alloc((size_t)NE * 768 * 4);   // k|q|v ent
    float* kqv_p = (float*)alloc((size_t)NP * 768 * 4);   // k|q|v psg
    float* kt_e  = (float*)alloc((size_t)NE * 256 * 4);
    float* vt_e  = (float*)alloc((size_t)NE * 256 * 4);
    float* kt_p  = (float*)alloc((size_t)NP * 256 * 4);
    float* vt_p  = (float*)alloc((size_t)NP * 256 * 4);
    float* agg_p = (float*)alloc((size_t)NP * 256 * 4);
    float* agg_e = (float*)alloc((size_t)NE * 256 * 4);
    float* h_ent = (float*)alloc((size_t)NE * 256 * 4);
    float* h_psg = (float*)alloc((size_t)NP * 256 * 4);
    float* qkv_m = (float*)alloc((size_t)NE * 768 * 4);   // q|k|v mha
    float* att_o = (float*)alloc((size_t)NE * 256 * 4);
    float* h_glob= (float*)alloc((size_t)NE * 256 * 4);
    float* relv  = (float*)alloc((size_t)NE * 4);
    float* ctxb  = (float*)alloc((size_t)NP * 256 * 4);
    float* qterm = (float*)alloc(256 * 4);
    int* cnt_a = (int*)alloc((size_t)NP * 4);
    int* cur_a = (int*)alloc((size_t)NP * 4);
    int* ip_a  = (int*)alloc((size_t)(NP + 1) * 4);
    int* ss_a  = (int*)alloc((size_t)E * 4);
    int* cnt_b = (int*)alloc((size_t)NE * 4);
    int* cur_b = (int*)alloc((size_t)NE * 4);
    int* ip_b  = (int*)alloc((size_t)(NE + 1) * 4);
    int* ss_b  = (int*)alloc((size_t)E * 4);

    hipMemsetAsync(cnt_a, 0, (size_t)NP * 4, stream);
    hipMemsetAsync(cnt_b, 0, (size_t)NE * 4, stream);
    hipMemsetAsync(d_out, 0, (size_t)out_size * 4, stream);

    const int eb = (E + 255) / 256;
    // CSR by dst for both edge types
    edge_count_kernel<<<eb, 256, 0, stream>>>(e2p_dst, cnt_a, E);
    edge_count_kernel<<<eb, 256, 0, stream>>>(p2e_dst, cnt_b, E);
    scan_kernel<<<1, 1024, 0, stream>>>(cnt_a, ip_a, cur_a);
    scan_kernel<<<1, 1024, 0, stream>>>(cnt_b, ip_b, cur_b);
    edge_scatter_kernel<<<eb, 256, 0, stream>>>(e2p_src, e2p_dst, cur_a, ss_a, E);
    edge_scatter_kernel<<<eb, 256, 0, stream>>>(p2e_src, p2e_dst, cur_b, ss_b, E);

    // HGT k|q|v projections (fused 3-weight GEMMs)
    gemm_kernel<0,0><<<dim3(12, NE / 64), 256, 0, stream>>>(
        x_ent, 256, Wk_e, Wq_e, Wv_e, 256, bk_e, bq_e, bv_e,
        kqv_e, 768, 256, nullptr, nullptr, nullptr, nullptr, nullptr);
    gemm_kernel<0,0><<<dim3(12, NP / 64), 256, 0, stream>>>(
        x_psg, 256, Wk_p, Wq_p, Wv_p, 256, bk_p, bq_p, bv_p,
        kqv_p, 768, 256, nullptr, nullptr, nullptr, nullptr, nullptr);

    // relation transforms (k with a_rel, v with m_rel)
    rel_transform_kernel<<<dim3(NE / 64, NHEAD), 256, 0, stream>>>(kqv_e + 0,   768, a_e2p, kt_e);
    rel_transform_kernel<<<dim3(NE / 64, NHEAD), 256, 0, stream>>>(kqv_e + 512, 768, m_e2p, vt_e);
    rel_transform_kernel<<<dim3(NP / 64, NHEAD), 256, 0, stream>>>(kqv_p + 0,   768, a_p2e, kt_p);
    rel_transform_kernel<<<dim3(NP / 64, NHEAD), 256, 0, stream>>>(kqv_p + 512, 768, m_p2e, vt_p);

    // per-dst softmax aggregation
    hgt_attn_kernel<<<NP, 256, 0, stream>>>(kqv_p + 256, kt_e, vt_e, p_e2p, ip_a, ss_a, agg_p);
    hgt_attn_kernel<<<NE, 256, 0, stream>>>(kqv_e + 256, kt_p, vt_p, p_p2e, ip_b, ss_b, agg_e);

    // HGT output: gelu -> Wout -> sigmoid-skip mix
    gemm_kernel<1,1><<<dim3(4, NE / 64), 256, 0, stream>>>(
        agg_e, 256, Wo_e, Wo_e, Wo_e, 256, bo_e, bo_e, bo_e,
        h_ent, 256, 256, x_ent, sk_e, nullptr, nullptr, nullptr);
    gemm_kernel<1,1><<<dim3(4, NP / 64), 256, 0, stream>>>(
        agg_p, 256, Wo_p, Wo_p, Wo_p, 256, bo_p, bo_p, bo_p,
        h_psg, 256, 256, x_psg, sk_p, nullptr, nullptr, nullptr);

    // MHA: fused qkv projection, flash attention, output projection
    gemm_kernel<0,0><<<dim3(12, NE / 64), 256, 0, stream>>>(
        h_ent, 256, Wmi, Wmi + 65536, Wmi + 131072, 256, bmi, bmi + 256, bmi + 512,
        qkv_m, 768, 256, nullptr, nullptr, nullptr, nullptr, nullptr);
    mha_flash_kernel<<<dim3(NE / 32, NHEAD), 256, 0, stream>>>(qkv_m, att_o, NE);
    gemm_kernel<0,0><<<dim3(4, NE / 64), 256, 0, stream>>>(
        att_o, 256, Wmo, Wmo, Wmo, 256, bmo, bmo, bmo,
        h_glob, 256, 256, nullptr, nullptr, nullptr, nullptr, nullptr);

    // residual mix + LN + relevance
    mix_ln_rel_kernel<<<NE / 4, 256, 0, stream>>>(h_ent, h_glob, lng_e, lnb_e, q_emb, relv);

    // gather-scale-scatter (reuses e2p CSR) + passage LN
    ctx_gather_kernel<<<NP, 256, 0, stream>>>(h_ent, relv, ip_a, ss_a, ctxb);
    psg_ln_kernel<<<NP / 4, 256, 0, stream>>>(h_psg, ctxb, lng_p, lnb_p);

    // scoring head
    qterm_kernel<<<1, 256, 0, stream>>>(w1, b1, q_emb, qterm);
    gemm_kernel<0,2><<<dim3(4, NP / 64), 256, 0, stream>>>(
        h_psg, 256, w1, w1, w1, 512, qterm, qterm, qterm,
        nullptr, 256, 256, nullptr, nullptr, scores, w2, b2);
}

// Round 4
// 871.419 us; speedup vs baseline: 1.3830x; 1.3830x over previous
//
#include <hip/hip_runtime.h>
#include <hip/hip_bf16.h>
#include <math.h>

#define DIM 256
#define NHEAD 4
#define HD 64

typedef __attribute__((ext_vector_type(8))) short short8b;   // 8 bf16 (4 VGPRs)
typedef __attribute__((ext_vector_type(4))) float f32x4;

union B8 { uint4 u; short8b v; };

__device__ __forceinline__ float sigmoidf_(float x) { return 1.0f / (1.0f + __expf(-x)); }
__device__ __forceinline__ float geluf_(float x) {
    return 0.5f * x * (1.0f + erff(x * 0.70710678118654752440f));
}
__device__ __forceinline__ float wave_sum64(float v) {
    v += __shfl_xor(v, 32); v += __shfl_xor(v, 16); v += __shfl_xor(v, 8);
    v += __shfl_xor(v, 4);  v += __shfl_xor(v, 2);  v += __shfl_xor(v, 1);
    return v;
}
__device__ __forceinline__ unsigned short f2bf(float f) {   // RNE f32->bf16 bits
    union { float f; unsigned int u; } a; a.f = f;
    unsigned int u = a.u;
    unsigned int r = (u + 0x7FFFu + ((u >> 16) & 1u)) >> 16;
    return (unsigned short)r;
}
__device__ __forceinline__ unsigned int pk2bf(float lo, float hi) {
    return (unsigned int)f2bf(lo) | ((unsigned int)f2bf(hi) << 16);
}

// ---------------------------------------------------------------------------
// Generic fp32 GEMM: C[N,Kout] = epilogue( act(A[N,Kin]) @ W^T + bias )
// W selected per 256-col chunk (lets one launch fuse k|q|v projections).
// OUT_MODE 0: C = acc+bias (WBF=1 also writes bf16 mirror Cbf)
// OUT_MODE 1: C = sig(skip)*(acc+bias) + (1-sig)*xres     (HGT out)
// OUT_MODE 2: scores[r] += relu(acc+bias) . w2  (+b2 once) (scoring head)
// IN_GELU 1: exact gelu applied to A elements on load.
// ---------------------------------------------------------------------------
template<int IN_GELU, int OUT_MODE, int WBF>
__launch_bounds__(256)
__global__ void gemm_kernel(const float* __restrict__ A, int lda,
                            const float* __restrict__ W0, const float* __restrict__ W1,
                            const float* __restrict__ W2, int ldw,
                            const float* __restrict__ B0, const float* __restrict__ B1,
                            const float* __restrict__ B2,
                            float* __restrict__ C, int ldc, int Kin,
                            const float* __restrict__ xres,
                            const float* __restrict__ skipv,
                            float* __restrict__ scores,
                            const float* __restrict__ w2v,
                            const float* __restrict__ b2v,
                            unsigned short* __restrict__ Cbf)
{
    __shared__ float As[16][68];
    __shared__ float Ws[16][68];
    const int t = threadIdx.x;
    const int r0 = blockIdx.y * 64;
    const int c0 = blockIdx.x * 64;
    const int widx = c0 >> 8;
    const float* W  = (widx == 0) ? W0 : (widx == 1 ? W1 : W2);
    const float* Bv = (widx == 0) ? B0 : (widx == 1 ? B1 : B2);
    const int cw = c0 & 255;

    const int lrow = t >> 2;          // 0..63
    const int lk   = (t & 3) << 2;    // 0,4,8,12
    const int ty = t >> 4, tx = t & 15;

    const float* Aptr = A + (size_t)(r0 + lrow) * lda + lk;
    const float* Wptr = W + (size_t)(cw + lrow) * ldw + lk;

    float acc[4][4] = {};
    for (int k0 = 0; k0 < Kin; k0 += 16) {
        float4 av = *reinterpret_cast<const float4*>(Aptr + k0);
        float4 wv = *reinterpret_cast<const float4*>(Wptr + k0);
        if (IN_GELU) {
            av.x = geluf_(av.x); av.y = geluf_(av.y);
            av.z = geluf_(av.z); av.w = geluf_(av.w);
        }
        As[lk + 0][lrow] = av.x; As[lk + 1][lrow] = av.y;
        As[lk + 2][lrow] = av.z; As[lk + 3][lrow] = av.w;
        Ws[lk + 0][lrow] = wv.x; Ws[lk + 1][lrow] = wv.y;
        Ws[lk + 2][lrow] = wv.z; Ws[lk + 3][lrow] = wv.w;
        __syncthreads();
#pragma unroll
        for (int k = 0; k < 16; ++k) {
            const float4 a = *reinterpret_cast<const float4*>(&As[k][ty << 2]);
            const float4 b = *reinterpret_cast<const float4*>(&Ws[k][tx << 2]);
            const float ar[4] = {a.x, a.y, a.z, a.w};
            const float br[4] = {b.x, b.y, b.z, b.w};
#pragma unroll
            for (int i = 0; i < 4; ++i)
#pragma unroll
                for (int j = 0; j < 4; ++j)
                    acc[i][j] = fmaf(ar[i], br[j], acc[i][j]);
        }
        __syncthreads();
    }

    float bias[4];
#pragma unroll
    for (int j = 0; j < 4; ++j) bias[j] = Bv[cw + (tx << 2) + j];

    if (OUT_MODE == 0) {
#pragma unroll
        for (int i = 0; i < 4; ++i) {
            const int r = r0 + (ty << 2) + i;
            float4 st;
            st.x = acc[i][0] + bias[0]; st.y = acc[i][1] + bias[1];
            st.z = acc[i][2] + bias[2]; st.w = acc[i][3] + bias[3];
            *reinterpret_cast<float4*>(&C[(size_t)r * ldc + c0 + (tx << 2)]) = st;
            if (WBF) {
                ushort4 sb;
                sb.x = f2bf(st.x); sb.y = f2bf(st.y); sb.z = f2bf(st.z); sb.w = f2bf(st.w);
                *reinterpret_cast<ushort4*>(&Cbf[(size_t)r * ldc + c0 + (tx << 2)]) = sb;
            }
        }
    } else if (OUT_MODE == 1) {
        const float sg = sigmoidf_(skipv[0]);
#pragma unroll
        for (int i = 0; i < 4; ++i) {
            const int r = r0 + (ty << 2) + i;
            const float4 xv = *reinterpret_cast<const float4*>(&xres[(size_t)r * ldc + c0 + (tx << 2)]);
            float4 st;
            st.x = sg * (acc[i][0] + bias[0]) + (1.f - sg) * xv.x;
            st.y = sg * (acc[i][1] + bias[1]) + (1.f - sg) * xv.y;
            st.z = sg * (acc[i][2] + bias[2]) + (1.f - sg) * xv.z;
            st.w = sg * (acc[i][3] + bias[3]) + (1.f - sg) * xv.w;
            *reinterpret_cast<float4*>(&C[(size_t)r * ldc + c0 + (tx << 2)]) = st;
        }
    } else {
        float wv[4];
#pragma unroll
        for (int j = 0; j < 4; ++j) wv[j] = w2v[c0 + (tx << 2) + j];
#pragma unroll
        for (int i = 0; i < 4; ++i) {
            float p = 0.f;
#pragma unroll
            for (int j = 0; j < 4; ++j)
                p = fmaf(fmaxf(acc[i][j] + bias[j], 0.f), wv[j], p);
            if (c0 == 0 && tx == 0) p += b2v[0];
            atomicAdd(&scores[r0 + (ty << 2) + i], p);
        }
    }
}

// ---------------------------------------------------------------------------
// kt[n, h*64+e] = sum_d kin[n, h*64+d] * arel[h, d, e]      (per-head 64x64)
// ---------------------------------------------------------------------------
__launch_bounds__(256)
__global__ void rel_transform_kernel(const float* __restrict__ kin, int ldin,
                                     const float* __restrict__ arel,
                                     float* __restrict__ kout)
{
    __shared__ float Al[64][68];   // [d][e]
    __shared__ float Kl[64][65];   // [r][d]
    const int t = threadIdx.x;
    const int r0 = blockIdx.x * 64;
    const int h = blockIdx.y;
    const float* ah = arel + h * 4096;
    for (int i = t; i < 1024; i += 256) {
        const int rr = i >> 4, c4 = (i & 15) << 2;
        const float4 av = *reinterpret_cast<const float4*>(&ah[rr * 64 + c4]);
        *reinterpret_cast<float4*>(&Al[rr][c4]) = av;
        const float4 kv = *reinterpret_cast<const float4*>(&kin[(size_t)(r0 + rr) * ldin + h * 64 + c4]);
        Kl[rr][c4 + 0] = kv.x; Kl[rr][c4 + 1] = kv.y;
        Kl[rr][c4 + 2] = kv.z; Kl[rr][c4 + 3] = kv.w;
    }
    __syncthreads();
    const int r  = t & 63;
    const int e0 = (t >> 6) << 4;   // 0,16,32,48
    float acc[16] = {};
    for (int d = 0; d < 64; ++d) {
        const float kv = Kl[r][d];
#pragma unroll
        for (int u4 = 0; u4 < 4; ++u4) {
            const float4 a = *reinterpret_cast<const float4*>(&Al[d][e0 + (u4 << 2)]);
            acc[u4 * 4 + 0] = fmaf(kv, a.x, acc[u4 * 4 + 0]);
            acc[u4 * 4 + 1] = fmaf(kv, a.y, acc[u4 * 4 + 1]);
            acc[u4 * 4 + 2] = fmaf(kv, a.z, acc[u4 * 4 + 2]);
            acc[u4 * 4 + 3] = fmaf(kv, a.w, acc[u4 * 4 + 3]);
        }
    }
#pragma unroll
    for (int u4 = 0; u4 < 4; ++u4) {
        float4 st = {acc[u4 * 4 + 0], acc[u4 * 4 + 1], acc[u4 * 4 + 2], acc[u4 * 4 + 3]};
        *reinterpret_cast<float4*>(&kout[(size_t)(r0 + r) * 256 + h * 64 + e0 + (u4 << 2)]) = st;
    }
}

// --------------------------- CSR build -------------------------------------
__global__ void edge_count_kernel(const int* __restrict__ dst, int* __restrict__ cnt, int E)
{
    const int i = blockIdx.x * 256 + threadIdx.x;
    if (i < E) atomicAdd(&cnt[dst[i]], 1);
}

__launch_bounds__(1024)
__global__ void scan_kernel(const int* __restrict__ cnt, int* __restrict__ indptr,
                            int* __restrict__ cursor)
{
    __shared__ int sh[1024];
    const int t = threadIdx.x;
    const int4 v = *reinterpret_cast<const int4*>(&cnt[t << 2]);
    const int sum = v.x + v.y + v.z + v.w;
    sh[t] = sum;
    __syncthreads();
    for (int off = 1; off < 1024; off <<= 1) {
        int x = 0;
        if (t >= off) x = sh[t - off];
        __syncthreads();
        if (t >= off) sh[t] += x;
        __syncthreads();
    }
    int run = sh[t] - sum;   // exclusive prefix of this thread's group
    const int base = t << 2;
    if (t == 0) indptr[0] = 0;
    cursor[base + 0] = run; run += v.x; indptr[base + 1] = run;
    cursor[base + 1] = run; run += v.y; indptr[base + 2] = run;
    cursor[base + 2] = run; run += v.z; indptr[base + 3] = run;
    cursor[base + 3] = run; run += v.w; indptr[base + 4] = run;
}

__global__ void edge_scatter_kernel(const int* __restrict__ src, const int* __restrict__ dst,
                                    int* __restrict__ cursor, int* __restrict__ ssrc, int E)
{
    const int i = blockIdx.x * 256 + threadIdx.x;
    if (i < E) {
        const int p = atomicAdd(&cursor[dst[i]], 1);
        ssrc[p] = src[i];
    }
}

// ---------------------------------------------------------------------------
// HGT edge softmax-aggregate: one wave per (dst node, head), lane = d.
// ---------------------------------------------------------------------------
__launch_bounds__(256)
__global__ void hgt_attn_kernel(const float* __restrict__ qdst,
                                const float* __restrict__ kt,
                                const float* __restrict__ vt,
                                const float* __restrict__ prel,
                                const int* __restrict__ indptr,
                                const int* __restrict__ ssrc,
                                float* __restrict__ agg)
{
    const int gw = (blockIdx.x * 256 + threadIdx.x) >> 6;
    const int lane = threadIdx.x & 63;
    const int n = gw >> 2;
    const int h = gw & 3;
    const float q = qdst[(size_t)n * 768 + h * 64 + lane];
    const float ps = prel[h] * 0.125f;                 // p_rel / sqrt(64)
    const int e0 = indptr[n], e1 = indptr[n + 1];
    float m = -1e30f, s = 0.f, acc = 0.f;
    for (int e = e0; e < e1; ++e) {
        const int sr = ssrc[e];
        float d = q * kt[(size_t)sr * 256 + h * 64 + lane];
        d = wave_sum64(d);
        const float logit = d * ps;
        const float mn = fmaxf(m, logit);
        const float f = __expf(m - mn);
        const float p = __expf(logit - mn);
        s = s * f + p;
        acc = acc * f + p * vt[(size_t)sr * 256 + h * 64 + lane];
        m = mn;
    }
    agg[(size_t)n * 256 + h * 64 + lane] = acc / (s + 1e-16f);
}

// ---------------------------------------------------------------------------
// V transpose: qkv_bf [N][768] (v section) -> vt[h*64+d][key]  (bf16)
// ---------------------------------------------------------------------------
__launch_bounds__(256)
__global__ void vtrans_kernel(const unsigned short* __restrict__ qkv_bf,
                              unsigned short* __restrict__ vt, int N)
{
    __shared__ unsigned short tile[64][66];
    const int t = threadIdx.x;
    const int k0 = blockIdx.x * 64;
    const int h = blockIdx.y;
    {
        const int key = t >> 2;
        const int d0 = (t & 3) << 4;
        const unsigned short* src = qkv_bf + (size_t)(k0 + key) * 768 + 512 + h * 64 + d0;
        const uint4 a = *reinterpret_cast<const uint4*>(src);
        const uint4 b = *reinterpret_cast<const uint4*>(src + 8);
        const unsigned int w_[8] = {a.x, a.y, a.z, a.w, b.x, b.y, b.z, b.w};
#pragma unroll
        for (int j = 0; j < 8; ++j) {
            tile[d0 + 2 * j][key]     = (unsigned short)(w_[j] & 0xffff);
            tile[d0 + 2 * j + 1][key] = (unsigned short)(w_[j] >> 16);
        }
    }
    __syncthreads();
    {
        const int d = t >> 2;
        const int kk = (t & 3) << 4;
        unsigned int o_[8];
#pragma unroll
        for (int j = 0; j < 8; ++j)
            o_[j] = (unsigned int)tile[d][kk + 2 * j] | ((unsigned int)tile[d][kk + 2 * j + 1] << 16);
        unsigned short* dstp = vt + (size_t)(h * 64 + d) * N + k0 + kk;
        uint4 s0 = {o_[0], o_[1], o_[2], o_[3]};
        uint4 s1 = {o_[4], o_[5], o_[6], o_[7]};
        *reinterpret_cast<uint4*>(dstp) = s0;
        *reinterpret_cast<uint4*>(dstp + 8) = s1;
    }
}

// ---------------------------------------------------------------------------
// MHA via bf16 MFMA (16x16x32), swapped operands: S^T = K·Q^T.
// One wave = 16 q-rows of one head; loops 32-key chunks; fp32 online softmax.
// No LDS, no barriers: K frags and V^T frags read straight from L2.
// ---------------------------------------------------------------------------
__launch_bounds__(256)
__global__ void mha_mfma_kernel(const unsigned short* __restrict__ qkv_bf, // [N][768]
                                const unsigned short* __restrict__ vt_bf,  // [256][N]
                                float* __restrict__ outp, int N)
{
    const int lane = threadIdx.x & 63;
    const int g = lane >> 4;            // lane group 0..3
    const int q15 = lane & 15;
    const int gw = blockIdx.x * 4 + (threadIdx.x >> 6);
    const int h = gw >> 8;              // 256 q-tiles per head (N=4096)
    const int qt = gw & 255;
    const int q0 = qt * 16;

    // Q B-frags: lane holds Q[q0+q15][kb*32 + 8g .. +7]
    B8 qf0, qf1;
    {
        const unsigned short* qp = qkv_bf + (size_t)(q0 + q15) * 768 + h * 64 + g * 8;
        qf0.u = *reinterpret_cast<const uint4*>(qp);
        qf1.u = *reinterpret_cast<const uint4*>(qp + 32);
    }

    f32x4 o0 = {0,0,0,0}, o1 = {0,0,0,0}, o2 = {0,0,0,0}, o3 = {0,0,0,0};
    float m_run = -1e30f, l_run = 0.f;

    const unsigned short* kbase = qkv_bf + 256 + h * 64 + g * 8;
    const unsigned short* vbase = vt_bf + (size_t)(h * 64 + q15) * N + g * 8;
    const int sl0 = (((2 * g) & 3) << 4) + q15;
    const int sl1 = (((2 * g + 1) & 3) << 4) + q15;

    for (int ck = 0; ck < N; ck += 32) {
        // ---- S^T = K·Q^T : two 16-key tiles, K=64 over d (2 mfma each) ----
        B8 k00, k01, k10, k11;
        const unsigned short* kp0 = kbase + (size_t)(ck + q15) * 768;
        const unsigned short* kp1 = kbase + (size_t)(ck + 16 + q15) * 768;
        k00.u = *reinterpret_cast<const uint4*>(kp0);
        k01.u = *reinterpret_cast<const uint4*>(kp0 + 32);
        k10.u = *reinterpret_cast<const uint4*>(kp1);
        k11.u = *reinterpret_cast<const uint4*>(kp1 + 32);
        f32x4 s0 = {0,0,0,0}, s1 = {0,0,0,0};
        s0 = __builtin_amdgcn_mfma_f32_16x16x32_bf16(k00.v, qf0.v, s0, 0, 0, 0);
        s0 = __builtin_amdgcn_mfma_f32_16x16x32_bf16(k01.v, qf1.v, s0, 0, 0, 0);
        s1 = __builtin_amdgcn_mfma_f32_16x16x32_bf16(k10.v, qf0.v, s1, 0, 0, 0);
        s1 = __builtin_amdgcn_mfma_f32_16x16x32_bf16(k11.v, qf1.v, s1, 0, 0, 0);

        // lane holds 8 logits for q-col q15: keys ck + {4g+r} and ck+16+{4g+r}
        float p[8];
        p[0] = s0.x * 0.125f; p[1] = s0.y * 0.125f; p[2] = s0.z * 0.125f; p[3] = s0.w * 0.125f;
        p[4] = s1.x * 0.125f; p[5] = s1.y * 0.125f; p[6] = s1.z * 0.125f; p[7] = s1.w * 0.125f;

        float mx = fmaxf(fmaxf(fmaxf(p[0], p[1]), fmaxf(p[2], p[3])),
                         fmaxf(fmaxf(p[4], p[5]), fmaxf(p[6], p[7])));
        mx = fmaxf(mx, __shfl_xor(mx, 16));
        mx = fmaxf(mx, __shfl_xor(mx, 32));
        const float mnew = fmaxf(m_run, mx);
        const float f = __expf(m_run - mnew);
        float sum = 0.f;
#pragma unroll
        for (int i = 0; i < 8; ++i) { p[i] = __expf(p[i] - mnew); sum += p[i]; }
        sum += __shfl_xor(sum, 16);
        sum += __shfl_xor(sum, 32);
        l_run = l_run * f + sum;
        m_run = mnew;
        o0 *= f; o1 *= f; o2 *= f; o3 *= f;

        // ---- repack P^T (C-layout) -> B-frag layout via 8 packed shfls ----
        const unsigned int c01a = pk2bf(p[0], p[1]), c23a = pk2bf(p[2], p[3]);
        const unsigned int c01b = pk2bf(p[4], p[5]), c23b = pk2bf(p[6], p[7]);
        uint4 pu;
        {
            unsigned int x0, x1;
            x0 = (unsigned int)__shfl((int)c01a, sl0); x1 = (unsigned int)__shfl((int)c01b, sl0);
            pu.x = (g < 2) ? x0 : x1;
            x0 = (unsigned int)__shfl((int)c23a, sl0); x1 = (unsigned int)__shfl((int)c23b, sl0);
            pu.y = (g < 2) ? x0 : x1;
            x0 = (unsigned int)__shfl((int)c01a, sl1); x1 = (unsigned int)__shfl((int)c01b, sl1);
            pu.z = (g < 2) ? x0 : x1;
            x0 = (unsigned int)__shfl((int)c23a, sl1); x1 = (unsigned int)__shfl((int)c23b, sl1);
            pu.w = (g < 2) ? x0 : x1;
        }
        B8 pb; pb.u = pu;

        // ---- O^T += V^T · P^T : 4 d-tiles, K=32 keys ----
        const unsigned short* vp = vbase + ck;
        B8 vf;
        vf.u = *reinterpret_cast<const uint4*>(vp);
        o0 = __builtin_amdgcn_mfma_f32_16x16x32_bf16(vf.v, pb.v, o0, 0, 0, 0);
        vf.u = *reinterpret_cast<const uint4*>(vp + (size_t)16 * N);
        o1 = __builtin_amdgcn_mfma_f32_16x16x32_bf16(vf.v, pb.v, o1, 0, 0, 0);
        vf.u = *reinterpret_cast<const uint4*>(vp + (size_t)32 * N);
        o2 = __builtin_amdgcn_mfma_f32_16x16x32_bf16(vf.v, pb.v, o2, 0, 0, 0);
        vf.u = *reinterpret_cast<const uint4*>(vp + (size_t)48 * N);
        o3 = __builtin_amdgcn_mfma_f32_16x16x32_bf16(vf.v, pb.v, o3, 0, 0, 0);
    }

    const float inv = 1.f / l_run;
    float* op = outp + (size_t)(q0 + q15) * 256 + h * 64 + 4 * g;
#pragma unroll
    for (int r = 0; r < 4; ++r) {
        op[0 * 16 + r] = o0[r] * inv;
        op[1 * 16 + r] = o1[r] * inv;
        op[2 * 16 + r] = o2[r] * inv;
        op[3 * 16 + r] = o3[r] * inv;
    }
}

// ---------------------------------------------------------------------------
// h_ent = LN(0.9*h_ent + 0.1*h_glob); rel = sigmoid(h_ent . q). Wave per row.
// ---------------------------------------------------------------------------
__launch_bounds__(256)
__global__ void mix_ln_rel_kernel(float* __restrict__ he, const float* __restrict__ hg,
                                  const float* __restrict__ g, const float* __restrict__ b,
                                  const float* __restrict__ q, float* __restrict__ rel)
{
    const int row = (blockIdx.x * 256 + threadIdx.x) >> 6;
    const int lane = threadIdx.x & 63;
    const float4 a = *reinterpret_cast<const float4*>(&he[(size_t)row * 256 + (lane << 2)]);
    const float4 c = *reinterpret_cast<const float4*>(&hg[(size_t)row * 256 + (lane << 2)]);
    float4 v;
    v.x = 0.9f * a.x + 0.1f * c.x; v.y = 0.9f * a.y + 0.1f * c.y;
    v.z = 0.9f * a.z + 0.1f * c.z; v.w = 0.9f * a.w + 0.1f * c.w;
    const float mean = wave_sum64(v.x + v.y + v.z + v.w) * (1.f / 256.f);
    float4 d = {v.x - mean, v.y - mean, v.z - mean, v.w - mean};
    const float var = wave_sum64(d.x * d.x + d.y * d.y + d.z * d.z + d.w * d.w) * (1.f / 256.f);
    const float rs = rsqrtf(var + 1e-5f);
    const float4 gg = *reinterpret_cast<const float4*>(&g[lane << 2]);
    const float4 bb = *reinterpret_cast<const float4*>(&b[lane << 2]);
    float4 y = {d.x * rs * gg.x + bb.x, d.y * rs * gg.y + bb.y,
                d.z * rs * gg.z + bb.z, d.w * rs * gg.w + bb.w};
    *reinterpret_cast<float4*>(&he[(size_t)row * 256 + (lane << 2)]) = y;
    const float4 qq = *reinterpret_cast<const float4*>(&q[lane << 2]);
    const float dq = wave_sum64(y.x * qq.x + y.y * qq.y + y.z * qq.z + y.w * qq.w);
    if (lane == 0) rel[row] = sigmoidf_(dq);
}

// ctx[p] = sum_{e in seg(p)} h_ent[src]*rel[src]. Wave per (p, quarter).
__launch_bounds__(256)
__global__ void ctx_gather_kernel(const float* __restrict__ he, const float* __restrict__ rel,
                                  const int* __restrict__ indptr, const int* __restrict__ ssrc,
                                  float* __restrict__ ctx)
{
    const int gw = (blockIdx.x * 256 + threadIdx.x) >> 6;
    const int lane = threadIdx.x & 63;
    const int p = gw >> 2, qt = gw & 3;
    const int e0 = indptr[p], e1 = indptr[p + 1];
    float acc = 0.f;
    for (int e = e0; e < e1; ++e) {
        const int sr = ssrc[e];
        acc = fmaf(he[(size_t)sr * 256 + qt * 64 + lane], rel[sr], acc);
    }
    ctx[(size_t)p * 256 + qt * 64 + lane] = acc;
}

// h_psg = LN(h_psg + ctx). Wave per row.
__launch_bounds__(256)
__global__ void psg_ln_kernel(float* __restrict__ hp, const float* __restrict__ ctx,
                              const float* __restrict__ g, const float* __restrict__ b)
{
    const int row = (blockIdx.x * 256 + threadIdx.x) >> 6;
    const int lane = threadIdx.x & 63;
    const float4 a = *reinterpret_cast<const float4*>(&hp[(size_t)row * 256 + (lane << 2)]);
    const float4 c = *reinterpret_cast<const float4*>(&ctx[(size_t)row * 256 + (lane << 2)]);
    float4 v = {a.x + c.x, a.y + c.y, a.z + c.z, a.w + c.w};
    const float mean = wave_sum64(v.x + v.y + v.z + v.w) * (1.f / 256.f);
    float4 d = {v.x - mean, v.y - mean, v.z - mean, v.w - mean};
    const float var = wave_sum64(d.x * d.x + d.y * d.y + d.z * d.z + d.w * d.w) * (1.f / 256.f);
    const float rs = rsqrtf(var + 1e-5f);
    const float4 gg = *reinterpret_cast<const float4*>(&g[lane << 2]);
    const float4 bb = *reinterpret_cast<const float4*>(&b[lane << 2]);
    float4 y = {d.x * rs * gg.x + bb.x, d.y * rs * gg.y + bb.y,
                d.z * rs * gg.z + bb.z, d.w * rs * gg.w + bb.w};
    *reinterpret_cast<float4*>(&hp[(size_t)row * 256 + (lane << 2)]) = y;
}

// qterm[j] = b1[j] + w1[j, 256:512] . q
__global__ void qterm_kernel(const float* __restrict__ w1, const float* __restrict__ b1,
                             const float* __restrict__ q, float* __restrict__ qterm)
{
    __shared__ float qs[256];
    const int t = threadIdx.x;
    qs[t] = q[t];
    __syncthreads();
    float s = b1[t];
    for (int k = 0; k < 256; ++k) s = fmaf(w1[(size_t)t * 512 + 256 + k], qs[k], s);
    qterm[t] = s;
}

// ---------------------------------------------------------------------------
extern "C" void kernel_launch(void* const* d_in, const int* in_sizes, int n_in,
                              void* d_out, int out_size, void* d_ws, size_t ws_size,
                              hipStream_t stream)
{
    const float* x_ent = (const float*)d_in[0];
    const float* x_psg = (const float*)d_in[1];
    const float* q_emb = (const float*)d_in[2];
    const float* Wk_e = (const float*)d_in[3];  const float* bk_e = (const float*)d_in[4];
    const float* Wq_e = (const float*)d_in[5];  const float* bq_e = (const float*)d_in[6];
    const float* Wv_e = (const float*)d_in[7];  const float* bv_e = (const float*)d_in[8];
    const float* Wo_e = (const float*)d_in[9];  const float* bo_e = (const float*)d_in[10];
    const float* sk_e = (const float*)d_in[11];
    const float* Wk_p = (const float*)d_in[12]; const float* bk_p = (const float*)d_in[13];
    const float* Wq_p = (const float*)d_in[14]; const float* bq_p = (const float*)d_in[15];
    const float* Wv_p = (const float*)d_in[16]; const float* bv_p = (const float*)d_in[17];
    const float* Wo_p = (const float*)d_in[18]; const float* bo_p = (const float*)d_in[19];
    const float* sk_p = (const float*)d_in[20];
    const float* a_e2p = (const float*)d_in[21];
    const float* m_e2p = (const float*)d_in[22];
    const float* p_e2p = (const float*)d_in[23];
    const float* a_p2e = (const float*)d_in[24];
    const float* m_p2e = (const float*)d_in[25];
    const float* p_p2e = (const float*)d_in[26];
    const float* Wmi = (const float*)d_in[27];  const float* bmi = (const float*)d_in[28];
    const float* Wmo = (const float*)d_in[29];  const float* bmo = (const float*)d_in[30];
    const float* lng_e = (const float*)d_in[31]; const float* lnb_e = (const float*)d_in[32];
    const float* lng_p = (const float*)d_in[33]; const float* lnb_p = (const float*)d_in[34];
    const float* w1 = (const float*)d_in[35];   const float* b1 = (const float*)d_in[36];
    const float* w2 = (const float*)d_in[37];   const float* b2 = (const float*)d_in[38];
    const int* e2p_src = (const int*)d_in[39];
    const int* e2p_dst = (const int*)d_in[40];
    const int* p2e_src = (const int*)d_in[41];
    const int* p2e_dst = (const int*)d_in[42];

    const int NE = in_sizes[0] / DIM;
    const int NP = in_sizes[1] / DIM;
    const int E  = in_sizes[39];
    float* scores = (float*)d_out;

    char* wp = (char*)d_ws;
    auto alloc = [&](size_t bytes) -> void* {
        void* r = (void*)wp;
        wp += (bytes + 255) & ~(size_t)255;
        return r;
    };
    float* kqv_e = (float*)alloc((size_t)NE * 768 * 4);
    float* kqv_p = (float*)alloc((size_t)NP * 768 * 4);
    float* kt_e  = (float*)alloc((size_t)NE * 256 * 4);
    float* vt_e  = (float*)alloc((size_t)NE * 256 * 4);
    float* kt_p  = (float*)alloc((size_t)NP * 256 * 4);
    float* vt_p  = (float*)alloc((size_t)NP * 256 * 4);
    float* agg_p = (float*)alloc((size_t)NP * 256 * 4);
    float* agg_e = (float*)alloc((size_t)NE * 256 * 4);
    float* h_ent = (float*)alloc((size_t)NE * 256 * 4);
    float* h_psg = (float*)alloc((size_t)NP * 256 * 4);
    float* qkv_m = (float*)alloc((size_t)NE * 768 * 4);
    float* att_o = (float*)alloc((size_t)NE * 256 * 4);
    float* h_glob= (float*)alloc((size_t)NE * 256 * 4);
    float* relv  = (float*)alloc((size_t)NE * 4);
    float* ctxb  = (float*)alloc((size_t)NP * 256 * 4);
    float* qterm = (float*)alloc(256 * 4);
    unsigned short* qkv_bf = (unsigned short*)alloc((size_t)NE * 768 * 2);
    unsigned short* vt_bf  = (unsigned short*)alloc((size_t)256 * NE * 2);
    int* cnt_a = (int*)alloc((size_t)NP * 4);
    int* cur_a = (int*)alloc((size_t)NP * 4);
    int* ip_a  = (int*)alloc((size_t)(NP + 1) * 4);
    int* ss_a  = (int*)alloc((size_t)E * 4);
    int* cnt_b = (int*)alloc((size_t)NE * 4);
    int* cur_b = (int*)alloc((size_t)NE * 4);
    int* ip_b  = (int*)alloc((size_t)(NE + 1) * 4);
    int* ss_b  = (int*)alloc((size_t)E * 4);

    hipMemsetAsync(cnt_a, 0, (size_t)NP * 4, stream);
    hipMemsetAsync(cnt_b, 0, (size_t)NE * 4, stream);
    hipMemsetAsync(d_out, 0, (size_t)out_size * 4, stream);

    const int eb = (E + 255) / 256;
    edge_count_kernel<<<eb, 256, 0, stream>>>(e2p_dst, cnt_a, E);
    edge_count_kernel<<<eb, 256, 0, stream>>>(p2e_dst, cnt_b, E);
    scan_kernel<<<1, 1024, 0, stream>>>(cnt_a, ip_a, cur_a);
    scan_kernel<<<1, 1024, 0, stream>>>(cnt_b, ip_b, cur_b);
    edge_scatter_kernel<<<eb, 256, 0, stream>>>(e2p_src, e2p_dst, cur_a, ss_a, E);
    edge_scatter_kernel<<<eb, 256, 0, stream>>>(p2e_src, p2e_dst, cur_b, ss_b, E);

    // HGT k|q|v projections
    gemm_kernel<0,0,0><<<dim3(12, NE / 64), 256, 0, stream>>>(
        x_ent, 256, Wk_e, Wq_e, Wv_e, 256, bk_e, bq_e, bv_e,
        kqv_e, 768, 256, nullptr, nullptr, nullptr, nullptr, nullptr, nullptr);
    gemm_kernel<0,0,0><<<dim3(12, NP / 64), 256, 0, stream>>>(
        x_psg, 256, Wk_p, Wq_p, Wv_p, 256, bk_p, bq_p, bv_p,
        kqv_p, 768, 256, nullptr, nullptr, nullptr, nullptr, nullptr, nullptr);

    rel_transform_kernel<<<dim3(NE / 64, NHEAD), 256, 0, stream>>>(kqv_e + 0,   768, a_e2p, kt_e);
    rel_transform_kernel<<<dim3(NE / 64, NHEAD), 256, 0, stream>>>(kqv_e + 512, 768, m_e2p, vt_e);
    rel_transform_kernel<<<dim3(NP / 64, NHEAD), 256, 0, stream>>>(kqv_p + 0,   768, a_p2e, kt_p);
    rel_transform_kernel<<<dim3(NP / 64, NHEAD), 256, 0, stream>>>(kqv_p + 512, 768, m_p2e, vt_p);

    hgt_attn_kernel<<<NP, 256, 0, stream>>>(kqv_p + 256, kt_e, vt_e, p_e2p, ip_a, ss_a, agg_p);
    hgt_attn_kernel<<<NE, 256, 0, stream>>>(kqv_e + 256, kt_p, vt_p, p_p2e, ip_b, ss_b, agg_e);

    gemm_kernel<1,1,0><<<dim3(4, NE / 64), 256, 0, stream>>>(
        agg_e, 256, Wo_e, Wo_e, Wo_e, 256, bo_e, bo_e, bo_e,
        h_ent, 256, 256, x_ent, sk_e, nullptr, nullptr, nullptr, nullptr);
    gemm_kernel<1,1,0><<<dim3(4, NP / 64), 256, 0, stream>>>(
        agg_p, 256, Wo_p, Wo_p, Wo_p, 256, bo_p, bo_p, bo_p,
        h_psg, 256, 256, x_psg, sk_p, nullptr, nullptr, nullptr, nullptr);

    // MHA: qkv projection (fp32 + bf16 mirror), V-transpose, MFMA flash, out proj
    gemm_kernel<0,0,1><<<dim3(12, NE / 64), 256, 0, stream>>>(
        h_ent, 256, Wmi, Wmi + 65536, Wmi + 131072, 256, bmi, bmi + 256, bmi + 512,
        qkv_m, 768, 256, nullptr, nullptr, nullptr, nullptr, nullptr, qkv_bf);
    vtrans_kernel<<<dim3(NE / 64, NHEAD), 256, 0, stream>>>(qkv_bf, vt_bf, NE);
    mha_mfma_kernel<<<NE / 16, 256, 0, stream>>>(qkv_bf, vt_bf, att_o, NE);
    gemm_kernel<0,0,0><<<dim3(4, NE / 64), 256, 0, stream>>>(
        att_o, 256, Wmo, Wmo, Wmo, 256, bmo, bmo, bmo,
        h_glob, 256, 256, nullptr, nullptr, nullptr, nullptr, nullptr, nullptr);

    mix_ln_rel_kernel<<<NE / 4, 256, 0, stream>>>(h_ent, h_glob, lng_e, lnb_e, q_emb, relv);

    ctx_gather_kernel<<<NP, 256, 0, stream>>>(h_ent, relv, ip_a, ss_a, ctxb);
    psg_ln_kernel<<<NP / 4, 256, 0, stream>>>(h_psg, ctxb, lng_p, lnb_p);

    qterm_kernel<<<1, 256, 0, stream>>>(w1, b1, q_emb, qterm);
    gemm_kernel<0,2,0><<<dim3(4, NP / 64), 256, 0, stream>>>(
        h_psg, 256, w1, w1, w1, 512, qterm, qterm, qterm,
        nullptr, 256, 256, nullptr, nullptr, scores, w2, b2, nullptr);
}

// Round 5
// 758.602 us; speedup vs baseline: 1.5887x; 1.1487x over previous
//
#include <hip/hip_runtime.h>
#include <hip/hip_bf16.h>
#include <math.h>

#define DIM 256
#define NHEAD 4
#define HD 64
#define MSPLIT 4

typedef __attribute__((ext_vector_type(8))) short short8b;   // 8 bf16 (4 VGPRs)
typedef __attribute__((ext_vector_type(4))) float f32x4;

union B8 { uint4 u; short8b v; };

__device__ __forceinline__ float sigmoidf_(float x) { return 1.0f / (1.0f + __expf(-x)); }
__device__ __forceinline__ float geluf_(float x) {
    return 0.5f * x * (1.0f + erff(x * 0.70710678118654752440f));
}
__device__ __forceinline__ float wave_sum64(float v) {
    v += __shfl_xor(v, 32); v += __shfl_xor(v, 16); v += __shfl_xor(v, 8);
    v += __shfl_xor(v, 4);  v += __shfl_xor(v, 2);  v += __shfl_xor(v, 1);
    return v;
}
__device__ __forceinline__ unsigned short f2bf(float f) {   // RNE f32->bf16 bits
    union { float f; unsigned int u; } a; a.f = f;
    unsigned int u = a.u;
    unsigned int r = (u + 0x7FFFu + ((u >> 16) & 1u)) >> 16;
    return (unsigned short)r;
}
__device__ __forceinline__ unsigned int pk2bf(float lo, float hi) {
    return (unsigned int)f2bf(lo) | ((unsigned int)f2bf(hi) << 16);
}

// ---------------------------------------------------------------------------
// Generic fp32 GEMM: C[N,Kout] = epilogue( act(A[N,Kin]) @ W^T + bias )
// ---------------------------------------------------------------------------
template<int IN_GELU, int OUT_MODE, int WBF>
__launch_bounds__(256)
__global__ void gemm_kernel(const float* __restrict__ A, int lda,
                            const float* __restrict__ W0, const float* __restrict__ W1,
                            const float* __restrict__ W2, int ldw,
                            const float* __restrict__ B0, const float* __restrict__ B1,
                            const float* __restrict__ B2,
                            float* __restrict__ C, int ldc, int Kin,
                            const float* __restrict__ xres,
                            const float* __restrict__ skipv,
                            float* __restrict__ scores,
                            const float* __restrict__ w2v,
                            const float* __restrict__ b2v,
                            unsigned short* __restrict__ Cbf)
{
    __shared__ float As[16][68];
    __shared__ float Ws[16][68];
    const int t = threadIdx.x;
    const int r0 = blockIdx.y * 64;
    const int c0 = blockIdx.x * 64;
    const int widx = c0 >> 8;
    const float* W  = (widx == 0) ? W0 : (widx == 1 ? W1 : W2);
    const float* Bv = (widx == 0) ? B0 : (widx == 1 ? B1 : B2);
    const int cw = c0 & 255;

    const int lrow = t >> 2;          // 0..63
    const int lk   = (t & 3) << 2;    // 0,4,8,12
    const int ty = t >> 4, tx = t & 15;

    const float* Aptr = A + (size_t)(r0 + lrow) * lda + lk;
    const float* Wptr = W + (size_t)(cw + lrow) * ldw + lk;

    float acc[4][4] = {};
    for (int k0 = 0; k0 < Kin; k0 += 16) {
        float4 av = *reinterpret_cast<const float4*>(Aptr + k0);
        float4 wv = *reinterpret_cast<const float4*>(Wptr + k0);
        if (IN_GELU) {
            av.x = geluf_(av.x); av.y = geluf_(av.y);
            av.z = geluf_(av.z); av.w = geluf_(av.w);
        }
        As[lk + 0][lrow] = av.x; As[lk + 1][lrow] = av.y;
        As[lk + 2][lrow] = av.z; As[lk + 3][lrow] = av.w;
        Ws[lk + 0][lrow] = wv.x; Ws[lk + 1][lrow] = wv.y;
        Ws[lk + 2][lrow] = wv.z; Ws[lk + 3][lrow] = wv.w;
        __syncthreads();
#pragma unroll
        for (int k = 0; k < 16; ++k) {
            const float4 a = *reinterpret_cast<const float4*>(&As[k][ty << 2]);
            const float4 b = *reinterpret_cast<const float4*>(&Ws[k][tx << 2]);
            const float ar[4] = {a.x, a.y, a.z, a.w};
            const float br[4] = {b.x, b.y, b.z, b.w};
#pragma unroll
            for (int i = 0; i < 4; ++i)
#pragma unroll
                for (int j = 0; j < 4; ++j)
                    acc[i][j] = fmaf(ar[i], br[j], acc[i][j]);
        }
        __syncthreads();
    }

    float bias[4];
#pragma unroll
    for (int j = 0; j < 4; ++j) bias[j] = Bv[cw + (tx << 2) + j];

    if (OUT_MODE == 0) {
#pragma unroll
        for (int i = 0; i < 4; ++i) {
            const int r = r0 + (ty << 2) + i;
            float4 st;
            st.x = acc[i][0] + bias[0]; st.y = acc[i][1] + bias[1];
            st.z = acc[i][2] + bias[2]; st.w = acc[i][3] + bias[3];
            *reinterpret_cast<float4*>(&C[(size_t)r * ldc + c0 + (tx << 2)]) = st;
            if (WBF) {
                ushort4 sb;
                sb.x = f2bf(st.x); sb.y = f2bf(st.y); sb.z = f2bf(st.z); sb.w = f2bf(st.w);
                *reinterpret_cast<ushort4*>(&Cbf[(size_t)r * ldc + c0 + (tx << 2)]) = sb;
            }
        }
    } else if (OUT_MODE == 1) {
        const float sg = sigmoidf_(skipv[0]);
#pragma unroll
        for (int i = 0; i < 4; ++i) {
            const int r = r0 + (ty << 2) + i;
            const float4 xv = *reinterpret_cast<const float4*>(&xres[(size_t)r * ldc + c0 + (tx << 2)]);
            float4 st;
            st.x = sg * (acc[i][0] + bias[0]) + (1.f - sg) * xv.x;
            st.y = sg * (acc[i][1] + bias[1]) + (1.f - sg) * xv.y;
            st.z = sg * (acc[i][2] + bias[2]) + (1.f - sg) * xv.z;
            st.w = sg * (acc[i][3] + bias[3]) + (1.f - sg) * xv.w;
            *reinterpret_cast<float4*>(&C[(size_t)r * ldc + c0 + (tx << 2)]) = st;
        }
    } else {
        float wv[4];
#pragma unroll
        for (int j = 0; j < 4; ++j) wv[j] = w2v[c0 + (tx << 2) + j];
#pragma unroll
        for (int i = 0; i < 4; ++i) {
            float p = 0.f;
#pragma unroll
            for (int j = 0; j < 4; ++j)
                p = fmaf(fmaxf(acc[i][j] + bias[j], 0.f), wv[j], p);
            if (c0 == 0 && tx == 0) p += b2v[0];
            atomicAdd(&scores[r0 + (ty << 2) + i], p);
        }
    }
}

// ---------------------------------------------------------------------------
// kt[n, h*64+e] = sum_d kin[n, h*64+d] * arel[h, d, e]      (per-head 64x64)
// ---------------------------------------------------------------------------
__launch_bounds__(256)
__global__ void rel_transform_kernel(const float* __restrict__ kin, int ldin,
                                     const float* __restrict__ arel,
                                     float* __restrict__ kout)
{
    __shared__ float Al[64][68];   // [d][e]
    __shared__ float Kl[64][65];   // [r][d]
    const int t = threadIdx.x;
    const int r0 = blockIdx.x * 64;
    const int h = blockIdx.y;
    const float* ah = arel + h * 4096;
    for (int i = t; i < 1024; i += 256) {
        const int rr = i >> 4, c4 = (i & 15) << 2;
        const float4 av = *reinterpret_cast<const float4*>(&ah[rr * 64 + c4]);
        *reinterpret_cast<float4*>(&Al[rr][c4]) = av;
        const float4 kv = *reinterpret_cast<const float4*>(&kin[(size_t)(r0 + rr) * ldin + h * 64 + c4]);
        Kl[rr][c4 + 0] = kv.x; Kl[rr][c4 + 1] = kv.y;
        Kl[rr][c4 + 2] = kv.z; Kl[rr][c4 + 3] = kv.w;
    }
    __syncthreads();
    const int r  = t & 63;
    const int e0 = (t >> 6) << 4;   // 0,16,32,48
    float acc[16] = {};
    for (int d = 0; d < 64; ++d) {
        const float kv = Kl[r][d];
#pragma unroll
        for (int u4 = 0; u4 < 4; ++u4) {
            const float4 a = *reinterpret_cast<const float4*>(&Al[d][e0 + (u4 << 2)]);
            acc[u4 * 4 + 0] = fmaf(kv, a.x, acc[u4 * 4 + 0]);
            acc[u4 * 4 + 1] = fmaf(kv, a.y, acc[u4 * 4 + 1]);
            acc[u4 * 4 + 2] = fmaf(kv, a.z, acc[u4 * 4 + 2]);
            acc[u4 * 4 + 3] = fmaf(kv, a.w, acc[u4 * 4 + 3]);
        }
    }
#pragma unroll
    for (int u4 = 0; u4 < 4; ++u4) {
        float4 st = {acc[u4 * 4 + 0], acc[u4 * 4 + 1], acc[u4 * 4 + 2], acc[u4 * 4 + 3]};
        *reinterpret_cast<float4*>(&kout[(size_t)(r0 + r) * 256 + h * 64 + e0 + (u4 << 2)]) = st;
    }
}

// --------------------------- CSR build -------------------------------------
__global__ void edge_count_kernel(const int* __restrict__ dst, int* __restrict__ cnt, int E)
{
    const int i = blockIdx.x * 256 + threadIdx.x;
    if (i < E) atomicAdd(&cnt[dst[i]], 1);
}

__launch_bounds__(1024)
__global__ void scan_kernel(const int* __restrict__ cnt, int* __restrict__ indptr,
                            int* __restrict__ cursor)
{
    __shared__ int sh[1024];
    const int t = threadIdx.x;
    const int4 v = *reinterpret_cast<const int4*>(&cnt[t << 2]);
    const int sum = v.x + v.y + v.z + v.w;
    sh[t] = sum;
    __syncthreads();
    for (int off = 1; off < 1024; off <<= 1) {
        int x = 0;
        if (t >= off) x = sh[t - off];
        __syncthreads();
        if (t >= off) sh[t] += x;
        __syncthreads();
    }
    int run = sh[t] - sum;   // exclusive prefix of this thread's group
    const int base = t << 2;
    if (t == 0) indptr[0] = 0;
    cursor[base + 0] = run; run += v.x; indptr[base + 1] = run;
    cursor[base + 1] = run; run += v.y; indptr[base + 2] = run;
    cursor[base + 2] = run; run += v.z; indptr[base + 3] = run;
    cursor[base + 3] = run; run += v.w; indptr[base + 4] = run;
}

__global__ void edge_scatter_kernel(const int* __restrict__ src, const int* __restrict__ dst,
                                    int* __restrict__ cursor, int* __restrict__ ssrc, int E)
{
    const int i = blockIdx.x * 256 + threadIdx.x;
    if (i < E) {
        const int p = atomicAdd(&cursor[dst[i]], 1);
        ssrc[p] = src[i];
    }
}

// ---------------------------------------------------------------------------
// HGT edge softmax-aggregate: ONE wave per dst node, all 4 heads at once.
// lane = h*16 + d4  (h = lane>>4, d-quad = (lane&15)*4). Dot-product reduce
// is 4 shfl_xor steps within each 16-lane head group.
// ---------------------------------------------------------------------------
__launch_bounds__(256)
__global__ void hgt_attn_kernel(const float* __restrict__ qdst,   // q section base, ld=768
                                const float* __restrict__ kt,
                                const float* __restrict__ vt,
                                const float* __restrict__ prel,
                                const int* __restrict__ indptr,
                                const int* __restrict__ ssrc,
                                float* __restrict__ agg)
{
    const int n = blockIdx.x * 4 + (threadIdx.x >> 6);
    const int lane = threadIdx.x & 63;
    const int h = lane >> 4;
    const int d4 = (lane & 15) << 2;
    const float4 q = *reinterpret_cast<const float4*>(&qdst[(size_t)n * 768 + h * 64 + d4]);
    const float ps = prel[h] * 0.125f;                 // p_rel / sqrt(64)
    const int e0 = indptr[n], e1 = indptr[n + 1];
    float m = -1e30f, s = 0.f;
    float4 acc = {0.f, 0.f, 0.f, 0.f};
    for (int e = e0; e < e1; ++e) {
        const int sr = ssrc[e];
        const float4 k = *reinterpret_cast<const float4*>(&kt[(size_t)sr * 256 + h * 64 + d4]);
        float d = q.x * k.x + q.y * k.y + q.z * k.z + q.w * k.w;
        d += __shfl_xor(d, 1); d += __shfl_xor(d, 2);
        d += __shfl_xor(d, 4); d += __shfl_xor(d, 8);
        const float logit = d * ps;
        const float mn = fmaxf(m, logit);
        const float f = __expf(m - mn);
        const float p = __expf(logit - mn);
        s = s * f + p;
        const float4 v = *reinterpret_cast<const float4*>(&vt[(size_t)sr * 256 + h * 64 + d4]);
        acc.x = acc.x * f + p * v.x;
        acc.y = acc.y * f + p * v.y;
        acc.z = acc.z * f + p * v.z;
        acc.w = acc.w * f + p * v.w;
        m = mn;
    }
    const float inv = 1.f / (s + 1e-16f);
    float4 st = {acc.x * inv, acc.y * inv, acc.z * inv, acc.w * inv};
    *reinterpret_cast<float4*>(&agg[(size_t)n * 256 + h * 64 + d4]) = st;
}

// ---------------------------------------------------------------------------
// V transpose: qkv_bf [N][768] (v section) -> vt[h*64+d][key]  (bf16)
// ---------------------------------------------------------------------------
__launch_bounds__(256)
__global__ void vtrans_kernel(const unsigned short* __restrict__ qkv_bf,
                              unsigned short* __restrict__ vt, int N)
{
    __shared__ unsigned short tile[64][66];
    const int t = threadIdx.x;
    const int k0 = blockIdx.x * 64;
    const int h = blockIdx.y;
    {
        const int key = t >> 2;
        const int d0 = (t & 3) << 4;
        const unsigned short* src = qkv_bf + (size_t)(k0 + key) * 768 + 512 + h * 64 + d0;
        const uint4 a = *reinterpret_cast<const uint4*>(src);
        const uint4 b = *reinterpret_cast<const uint4*>(src + 8);
        const unsigned int w_[8] = {a.x, a.y, a.z, a.w, b.x, b.y, b.z, b.w};
#pragma unroll
        for (int j = 0; j < 8; ++j) {
            tile[d0 + 2 * j][key]     = (unsigned short)(w_[j] & 0xffff);
            tile[d0 + 2 * j + 1][key] = (unsigned short)(w_[j] >> 16);
        }
    }
    __syncthreads();
    {
        const int d = t >> 2;
        const int kk = (t & 3) << 4;
        unsigned int o_[8];
#pragma unroll
        for (int j = 0; j < 8; ++j)
            o_[j] = (unsigned int)tile[d][kk + 2 * j] | ((unsigned int)tile[d][kk + 2 * j + 1] << 16);
        unsigned short* dstp = vt + (size_t)(h * 64 + d) * N + k0 + kk;
        uint4 s0 = {o_[0], o_[1], o_[2], o_[3]};
        uint4 s1 = {o_[4], o_[5], o_[6], o_[7]};
        *reinterpret_cast<uint4*>(dstp) = s0;
        *reinterpret_cast<uint4*>(dstp + 8) = s1;
    }
}

// ---------------------------------------------------------------------------
// MHA via bf16 MFMA, flash-decoding split-K: wave = (q-tile, head, key-split).
// Writes raw O numerator + per-row (m, l); combine pass merges splits.
// Block = 4 waves = the 4 splits of one (head, q-tile): Q frags shared in L1.
// ---------------------------------------------------------------------------
__launch_bounds__(256)
__global__ void mha_mfma_kernel(const unsigned short* __restrict__ qkv_bf, // [N][768]
                                const unsigned short* __restrict__ vt_bf,  // [256][N]
                                float* __restrict__ opart,  // [MSPLIT][N][256]
                                float* __restrict__ mpart,  // [MSPLIT][NHEAD][N]
                                float* __restrict__ lpart,  // [MSPLIT][NHEAD][N]
                                int N)
{
    const int lane = threadIdx.x & 63;
    const int g = lane >> 4;            // lane group 0..3
    const int q15 = lane & 15;
    const int gw = blockIdx.x * 4 + (threadIdx.x >> 6);
    const int split = gw & (MSPLIT - 1);
    const int gq = gw >> 2;             // head * (N/16) + q-tile
    const int h = gq >> 8;              // N/16 = 256 q-tiles per head (N=4096)
    const int qt = gq & 255;
    const int q0 = qt * 16;
    const int kbeg = split * (N / MSPLIT);
    const int kend = kbeg + (N / MSPLIT);

    // Q B-frags: lane holds Q[q0+q15][kb*32 + 8g .. +7]
    B8 qf0, qf1;
    {
        const unsigned short* qp = qkv_bf + (size_t)(q0 + q15) * 768 + h * 64 + g * 8;
        qf0.u = *reinterpret_cast<const uint4*>(qp);
        qf1.u = *reinterpret_cast<const uint4*>(qp + 32);
    }

    f32x4 o0 = {0,0,0,0}, o1 = {0,0,0,0}, o2 = {0,0,0,0}, o3 = {0,0,0,0};
    float m_run = -1e30f, l_run = 0.f;

    const unsigned short* kbase = qkv_bf + 256 + h * 64 + g * 8;
    const unsigned short* vbase = vt_bf + (size_t)(h * 64 + q15) * N + g * 8;
    const int sl0 = (((2 * g) & 3) << 4) + q15;
    const int sl1 = (((2 * g + 1) & 3) << 4) + q15;

    for (int ck = kbeg; ck < kend; ck += 32) {
        // ---- S^T = K·Q^T : two 16-key tiles, K=64 over d (2 mfma each) ----
        B8 k00, k01, k10, k11;
        const unsigned short* kp0 = kbase + (size_t)(ck + q15) * 768;
        const unsigned short* kp1 = kbase + (size_t)(ck + 16 + q15) * 768;
        k00.u = *reinterpret_cast<const uint4*>(kp0);
        k01.u = *reinterpret_cast<const uint4*>(kp0 + 32);
        k10.u = *reinterpret_cast<const uint4*>(kp1);
        k11.u = *reinterpret_cast<const uint4*>(kp1 + 32);
        f32x4 s0 = {0,0,0,0}, s1 = {0,0,0,0};
        s0 = __builtin_amdgcn_mfma_f32_16x16x32_bf16(k00.v, qf0.v, s0, 0, 0, 0);
        s0 = __builtin_amdgcn_mfma_f32_16x16x32_bf16(k01.v, qf1.v, s0, 0, 0, 0);
        s1 = __builtin_amdgcn_mfma_f32_16x16x32_bf16(k10.v, qf0.v, s1, 0, 0, 0);
        s1 = __builtin_amdgcn_mfma_f32_16x16x32_bf16(k11.v, qf1.v, s1, 0, 0, 0);

        // lane holds 8 logits for q-col q15: keys ck + {4g+r} and ck+16+{4g+r}
        float p[8];
        p[0] = s0.x * 0.125f; p[1] = s0.y * 0.125f; p[2] = s0.z * 0.125f; p[3] = s0.w * 0.125f;
        p[4] = s1.x * 0.125f; p[5] = s1.y * 0.125f; p[6] = s1.z * 0.125f; p[7] = s1.w * 0.125f;

        float mx = fmaxf(fmaxf(fmaxf(p[0], p[1]), fmaxf(p[2], p[3])),
                         fmaxf(fmaxf(p[4], p[5]), fmaxf(p[6], p[7])));
        mx = fmaxf(mx, __shfl_xor(mx, 16));
        mx = fmaxf(mx, __shfl_xor(mx, 32));
        const float mnew = fmaxf(m_run, mx);
        const float f = __expf(m_run - mnew);
        float sum = 0.f;
#pragma unroll
        for (int i = 0; i < 8; ++i) { p[i] = __expf(p[i] - mnew); sum += p[i]; }
        sum += __shfl_xor(sum, 16);
        sum += __shfl_xor(sum, 32);
        l_run = l_run * f + sum;
        m_run = mnew;
        o0 *= f; o1 *= f; o2 *= f; o3 *= f;

        // ---- repack P^T (C-layout) -> B-frag layout via 8 packed shfls ----
        const unsigned int c01a = pk2bf(p[0], p[1]), c23a = pk2bf(p[2], p[3]);
        const unsigned int c01b = pk2bf(p[4], p[5]), c23b = pk2bf(p[6], p[7]);
        uint4 pu;
        {
            unsigned int x0, x1;
            x0 = (unsigned int)__shfl((int)c01a, sl0); x1 = (unsigned int)__shfl((int)c01b, sl0);
            pu.x = (g < 2) ? x0 : x1;
            x0 = (unsigned int)__shfl((int)c23a, sl0); x1 = (unsigned int)__shfl((int)c23b, sl0);
            pu.y = (g < 2) ? x0 : x1;
            x0 = (unsigned int)__shfl((int)c01a, sl1); x1 = (unsigned int)__shfl((int)c01b, sl1);
            pu.z = (g < 2) ? x0 : x1;
            x0 = (unsigned int)__shfl((int)c23a, sl1); x1 = (unsigned int)__shfl((int)c23b, sl1);
            pu.w = (g < 2) ? x0 : x1;
        }
        B8 pb; pb.u = pu;

        // ---- O^T += V^T · P^T : 4 d-tiles, K=32 keys ----
        const unsigned short* vp = vbase + ck;
        B8 vf;
        vf.u = *reinterpret_cast<const uint4*>(vp);
        o0 = __builtin_amdgcn_mfma_f32_16x16x32_bf16(vf.v, pb.v, o0, 0, 0, 0);
        vf.u = *reinterpret_cast<const uint4*>(vp + (size_t)16 * N);
        o1 = __builtin_amdgcn_mfma_f32_16x16x32_bf16(vf.v, pb.v, o1, 0, 0, 0);
        vf.u = *reinterpret_cast<const uint4*>(vp + (size_t)32 * N);
        o2 = __builtin_amdgcn_mfma_f32_16x16x32_bf16(vf.v, pb.v, o2, 0, 0, 0);
        vf.u = *reinterpret_cast<const uint4*>(vp + (size_t)48 * N);
        o3 = __builtin_amdgcn_mfma_f32_16x16x32_bf16(vf.v, pb.v, o3, 0, 0, 0);
    }

    float* op = opart + (size_t)split * N * 256 + (size_t)(q0 + q15) * 256 + h * 64 + 4 * g;
#pragma unroll
    for (int r = 0; r < 4; ++r) {
        op[0 * 16 + r] = o0[r];
        op[1 * 16 + r] = o1[r];
        op[2 * 16 + r] = o2[r];
        op[3 * 16 + r] = o3[r];
    }
    if (g == 0) {
        mpart[(size_t)(split * NHEAD + h) * N + q0 + q15] = m_run;
        lpart[(size_t)(split * NHEAD + h) * N + q0 + q15] = l_run;
    }
}

// Combine the MSPLIT partials: out = sum_s w_s O_s / sum_s w_s l_s.
__launch_bounds__(256)
__global__ void mha_combine_kernel(const float* __restrict__ opart,
                                   const float* __restrict__ mpart,
                                   const float* __restrict__ lpart,
                                   float* __restrict__ outp, int N)
{
    const int q = blockIdx.x;
    const int c = threadIdx.x;
    const int h = c >> 6;
    const size_t base = (size_t)q * 256 + c;
    float m[MSPLIT], l[MSPLIT];
    float M = -1e30f;
#pragma unroll
    for (int s = 0; s < MSPLIT; ++s) {
        m[s] = mpart[(size_t)(s * NHEAD + h) * N + q];
        l[s] = lpart[(size_t)(s * NHEAD + h) * N + q];
        M = fmaxf(M, m[s]);
    }
    float L = 0.f, o = 0.f;
#pragma unroll
    for (int s = 0; s < MSPLIT; ++s) {
        const float w = __expf(m[s] - M);
        L += w * l[s];
        o = fmaf(w, opart[(size_t)s * N * 256 + base], o);
    }
    outp[base] = o / L;
}

// ---------------------------------------------------------------------------
// h_ent = LN(0.9*h_ent + 0.1*h_glob); rel = sigmoid(h_ent . q). Wave per row.
// ---------------------------------------------------------------------------
__launch_bounds__(256)
__global__ void mix_ln_rel_kernel(float* __restrict__ he, const float* __restrict__ hg,
                                  const float* __restrict__ g, const float* __restrict__ b,
                                  const float* __restrict__ q, float* __restrict__ rel)
{
    const int row = (blockIdx.x * 256 + threadIdx.x) >> 6;
    const int lane = threadIdx.x & 63;
    const float4 a = *reinterpret_cast<const float4*>(&he[(size_t)row * 256 + (lane << 2)]);
    const float4 c = *reinterpret_cast<const float4*>(&hg[(size_t)row * 256 + (lane << 2)]);
    float4 v;
    v.x = 0.9f * a.x + 0.1f * c.x; v.y = 0.9f * a.y + 0.1f * c.y;
    v.z = 0.9f * a.z + 0.1f * c.z; v.w = 0.9f * a.w + 0.1f * c.w;
    const float mean = wave_sum64(v.x + v.y + v.z + v.w) * (1.f / 256.f);
    float4 d = {v.x - mean, v.y - mean, v.z - mean, v.w - mean};
    const float var = wave_sum64(d.x * d.x + d.y * d.y + d.z * d.z + d.w * d.w) * (1.f / 256.f);
    const float rs = rsqrtf(var + 1e-5f);
    const float4 gg = *reinterpret_cast<const float4*>(&g[lane << 2]);
    const float4 bb = *reinterpret_cast<const float4*>(&b[lane << 2]);
    float4 y = {d.x * rs * gg.x + bb.x, d.y * rs * gg.y + bb.y,
                d.z * rs * gg.z + bb.z, d.w * rs * gg.w + bb.w};
    *reinterpret_cast<float4*>(&he[(size_t)row * 256 + (lane << 2)]) = y;
    const float4 qq = *reinterpret_cast<const float4*>(&q[lane << 2]);
    const float dq = wave_sum64(y.x * qq.x + y.y * qq.y + y.z * qq.z + y.w * qq.w);
    if (lane == 0) rel[row] = sigmoidf_(dq);
}

// ctx[p] = sum_{e in seg(p)} h_ent[src]*rel[src]. Wave per (p, quarter).
__launch_bounds__(256)
__global__ void ctx_gather_kernel(const float* __restrict__ he, const float* __restrict__ rel,
                                  const int* __restrict__ indptr, const int* __restrict__ ssrc,
                                  float* __restrict__ ctx)
{
    const int gw = (blockIdx.x * 256 + threadIdx.x) >> 6;
    const int lane = threadIdx.x & 63;
    const int p = gw >> 2, qt = gw & 3;
    const int e0 = indptr[p], e1 = indptr[p + 1];
    float acc = 0.f;
    for (int e = e0; e < e1; ++e) {
        const int sr = ssrc[e];
        acc = fmaf(he[(size_t)sr * 256 + qt * 64 + lane], rel[sr], acc);
    }
    ctx[(size_t)p * 256 + qt * 64 + lane] = acc;
}

// h_psg = LN(h_psg + ctx). Wave per row.
__launch_bounds__(256)
__global__ void psg_ln_kernel(float* __restrict__ hp, const float* __restrict__ ctx,
                              const float* __restrict__ g, const float* __restrict__ b)
{
    const int row = (blockIdx.x * 256 + threadIdx.x) >> 6;
    const int lane = threadIdx.x & 63;
    const float4 a = *reinterpret_cast<const float4*>(&hp[(size_t)row * 256 + (lane << 2)]);
    const float4 c = *reinterpret_cast<const float4*>(&ctx[(size_t)row * 256 + (lane << 2)]);
    float4 v = {a.x + c.x, a.y + c.y, a.z + c.z, a.w + c.w};
    const float mean = wave_sum64(v.x + v.y + v.z + v.w) * (1.f / 256.f);
    float4 d = {v.x - mean, v.y - mean, v.z - mean, v.w - mean};
    const float var = wave_sum64(d.x * d.x + d.y * d.y + d.z * d.z + d.w * d.w) * (1.f / 256.f);
    const float rs = rsqrtf(var + 1e-5f);
    const float4 gg = *reinterpret_cast<const float4*>(&g[lane << 2]);
    const float4 bb = *reinterpret_cast<const float4*>(&b[lane << 2]);
    float4 y = {d.x * rs * gg.x + bb.x, d.y * rs * gg.y + bb.y,
                d.z * rs * gg.z + bb.z, d.w * rs * gg.w + bb.w};
    *reinterpret_cast<float4*>(&hp[(size_t)row * 256 + (lane << 2)]) = y;
}

// qterm[j] = b1[j] + w1[j, 256:512] . q
__global__ void qterm_kernel(const float* __restrict__ w1, const float* __restrict__ b1,
                             const float* __restrict__ q, float* __restrict__ qterm)
{
    __shared__ float qs[256];
    const int t = threadIdx.x;
    qs[t] = q[t];
    __syncthreads();
    float s = b1[t];
    for (int k = 0; k < 256; ++k) s = fmaf(w1[(size_t)t * 512 + 256 + k], qs[k], s);
    qterm[t] = s;
}

// ---------------------------------------------------------------------------
extern "C" void kernel_launch(void* const* d_in, const int* in_sizes, int n_in,
                              void* d_out, int out_size, void* d_ws, size_t ws_size,
                              hipStream_t stream)
{
    const float* x_ent = (const float*)d_in[0];
    const float* x_psg = (const float*)d_in[1];
    const float* q_emb = (const float*)d_in[2];
    const float* Wk_e = (const float*)d_in[3];  const float* bk_e = (const float*)d_in[4];
    const float* Wq_e = (const float*)d_in[5];  const float* bq_e = (const float*)d_in[6];
    const float* Wv_e = (const float*)d_in[7];  const float* bv_e = (const float*)d_in[8];
    const float* Wo_e = (const float*)d_in[9];  const float* bo_e = (const float*)d_in[10];
    const float* sk_e = (const float*)d_in[11];
    const float* Wk_p = (const float*)d_in[12]; const float* bk_p = (const float*)d_in[13];
    const float* Wq_p = (const float*)d_in[14]; const float* bq_p = (const float*)d_in[15];
    const float* Wv_p = (const float*)d_in[16]; const float* bv_p = (const float*)d_in[17];
    const float* Wo_p = (const float*)d_in[18]; const float* bo_p = (const float*)d_in[19];
    const float* sk_p = (const float*)d_in[20];
    const float* a_e2p = (const float*)d_in[21];
    const float* m_e2p = (const float*)d_in[22];
    const float* p_e2p = (const float*)d_in[23];
    const float* a_p2e = (const float*)d_in[24];
    const float* m_p2e = (const float*)d_in[25];
    const float* p_p2e = (const float*)d_in[26];
    const float* Wmi = (const float*)d_in[27];  const float* bmi = (const float*)d_in[28];
    const float* Wmo = (const float*)d_in[29];  const float* bmo = (const float*)d_in[30];
    const float* lng_e = (const float*)d_in[31]; const float* lnb_e = (const float*)d_in[32];
    const float* lng_p = (const float*)d_in[33]; const float* lnb_p = (const float*)d_in[34];
    const float* w1 = (const float*)d_in[35];   const float* b1 = (const float*)d_in[36];
    const float* w2 = (const float*)d_in[37];   const float* b2 = (const float*)d_in[38];
    const int* e2p_src = (const int*)d_in[39];
    const int* e2p_dst = (const int*)d_in[40];
    const int* p2e_src = (const int*)d_in[41];
    const int* p2e_dst = (const int*)d_in[42];

    const int NE = in_sizes[0] / DIM;
    const int NP = in_sizes[1] / DIM;
    const int E  = in_sizes[39];
    float* scores = (float*)d_out;

    char* wp = (char*)d_ws;
    auto alloc = [&](size_t bytes) -> void* {
        void* r = (void*)wp;
        wp += (bytes + 255) & ~(size_t)255;
        return r;
    };
    float* kqv_e = (float*)alloc((size_t)NE * 768 * 4);
    float* kqv_p = (float*)alloc((size_t)NP * 768 * 4);
    float* kt_e  = (float*)alloc((size_t)NE * 256 * 4);
    float* vt_e  = (float*)alloc((size_t)NE * 256 * 4);
    float* kt_p  = (float*)alloc((size_t)NP * 256 * 4);
    float* vt_p  = (float*)alloc((size_t)NP * 256 * 4);
    float* agg_p = (float*)alloc((size_t)NP * 256 * 4);
    float* agg_e = (float*)alloc((size_t)NE * 256 * 4);
    float* h_ent = (float*)alloc((size_t)NE * 256 * 4);
    float* h_psg = (float*)alloc((size_t)NP * 256 * 4);
    float* qkv_m = (float*)alloc((size_t)NE * 768 * 4);
    float* att_o = (float*)alloc((size_t)NE * 256 * 4);
    float* h_glob= (float*)alloc((size_t)NE * 256 * 4);
    float* relv  = (float*)alloc((size_t)NE * 4);
    float* ctxb  = (float*)alloc((size_t)NP * 256 * 4);
    float* qterm = (float*)alloc(256 * 4);
    unsigned short* qkv_bf = (unsigned short*)alloc((size_t)NE * 768 * 2);
    unsigned short* vt_bf  = (unsigned short*)alloc((size_t)256 * NE * 2);
    float* mpart = (float*)alloc((size_t)MSPLIT * NHEAD * NE * 4);
    float* lpart = (float*)alloc((size_t)MSPLIT * NHEAD * NE * 4);
    // opart (MSPLIT*NE*256 fp32 = 16 MB) aliases kqv_e+kqv_p (25 MB contiguous):
    // both are dead once the hgt_attn dispatches complete, before mha_mfma runs.
    float* opart = kqv_e;
    int* cnt_a = (int*)alloc((size_t)NP * 4);
    int* cur_a = (int*)alloc((size_t)NP * 4);
    int* ip_a  = (int*)alloc((size_t)(NP + 1) * 4);
    int* ss_a  = (int*)alloc((size_t)E * 4);
    int* cnt_b = (int*)alloc((size_t)NE * 4);
    int* cur_b = (int*)alloc((size_t)NE * 4);
    int* ip_b  = (int*)alloc((size_t)(NE + 1) * 4);
    int* ss_b  = (int*)alloc((size_t)E * 4);

    hipMemsetAsync(cnt_a, 0, (size_t)NP * 4, stream);
    hipMemsetAsync(cnt_b, 0, (size_t)NE * 4, stream);
    hipMemsetAsync(d_out, 0, (size_t)out_size * 4, stream);

    const int eb = (E + 255) / 256;
    edge_count_kernel<<<eb, 256, 0, stream>>>(e2p_dst, cnt_a, E);
    edge_count_kernel<<<eb, 256, 0, stream>>>(p2e_dst, cnt_b, E);
    scan_kernel<<<1, 1024, 0, stream>>>(cnt_a, ip_a, cur_a);
    scan_kernel<<<1, 1024, 0, stream>>>(cnt_b, ip_b, cur_b);
    edge_scatter_kernel<<<eb, 256, 0, stream>>>(e2p_src, e2p_dst, cur_a, ss_a, E);
    edge_scatter_kernel<<<eb, 256, 0, stream>>>(p2e_src, p2e_dst, cur_b, ss_b, E);

    // HGT k|q|v projections
    gemm_kernel<0,0,0><<<dim3(12, NE / 64), 256, 0, stream>>>(
        x_ent, 256, Wk_e, Wq_e, Wv_e, 256, bk_e, bq_e, bv_e,
        kqv_e, 768, 256, nullptr, nullptr, nullptr, nullptr, nullptr, nullptr);
    gemm_kernel<0,0,0><<<dim3(12, NP / 64), 256, 0, stream>>>(
        x_psg, 256, Wk_p, Wq_p, Wv_p, 256, bk_p, bq_p, bv_p,
        kqv_p, 768, 256, nullptr, nullptr, nullptr, nullptr, nullptr, nullptr);

    rel_transform_kernel<<<dim3(NE / 64, NHEAD), 256, 0, stream>>>(kqv_e + 0,   768, a_e2p, kt_e);
    rel_transform_kernel<<<dim3(NE / 64, NHEAD), 256, 0, stream>>>(kqv_e + 512, 768, m_e2p, vt_e);
    rel_transform_kernel<<<dim3(NP / 64, NHEAD), 256, 0, stream>>>(kqv_p + 0,   768, a_p2e, kt_p);
    rel_transform_kernel<<<dim3(NP / 64, NHEAD), 256, 0, stream>>>(kqv_p + 512, 768, m_p2e, vt_p);

    // per-dst softmax aggregation (one wave per node, 4 heads fused)
    hgt_attn_kernel<<<NP / 4, 256, 0, stream>>>(kqv_p + 256, kt_e, vt_e, p_e2p, ip_a, ss_a, agg_p);
    hgt_attn_kernel<<<NE / 4, 256, 0, stream>>>(kqv_e + 256, kt_p, vt_p, p_p2e, ip_b, ss_b, agg_e);

    gemm_kernel<1,1,0><<<dim3(4, NE / 64), 256, 0, stream>>>(
        agg_e, 256, Wo_e, Wo_e, Wo_e, 256, bo_e, bo_e, bo_e,
        h_ent, 256, 256, x_ent, sk_e, nullptr, nullptr, nullptr, nullptr);
    gemm_kernel<1,1,0><<<dim3(4, NP / 64), 256, 0, stream>>>(
        agg_p, 256, Wo_p, Wo_p, Wo_p, 256, bo_p, bo_p, bo_p,
        h_psg, 256, 256, x_psg, sk_p, nullptr, nullptr, nullptr, nullptr);

    // MHA: qkv projection (fp32 + bf16 mirror), V-transpose, split-K MFMA flash,
    // combine, out proj
    gemm_kernel<0,0,1><<<dim3(12, NE / 64), 256, 0, stream>>>(
        h_ent, 256, Wmi, Wmi + 65536, Wmi + 131072, 256, bmi, bmi + 256, bmi + 512,
        qkv_m, 768, 256, nullptr, nullptr, nullptr, nullptr, nullptr, qkv_bf);
    vtrans_kernel<<<dim3(NE / 64, NHEAD), 256, 0, stream>>>(qkv_bf, vt_bf, NE);
    mha_mfma_kernel<<<NHEAD * (NE / 16) * MSPLIT / 4, 256, 0, stream>>>(
        qkv_bf, vt_bf, opart, mpart, lpart, NE);
    mha_combine_kernel<<<NE, 256, 0, stream>>>(opart, mpart, lpart, att_o, NE);
    gemm_kernel<0,0,0><<<dim3(4, NE / 64), 256, 0, stream>>>(
        att_o, 256, Wmo, Wmo, Wmo, 256, bmo, bmo, bmo,
        h_glob, 256, 256, nullptr, nullptr, nullptr, nullptr, nullptr, nullptr);

    mix_ln_rel_kernel<<<NE / 4, 256, 0, stream>>>(h_ent, h_glob, lng_e, lnb_e, q_emb, relv);

    ctx_gather_kernel<<<NP, 256, 0, stream>>>(h_ent, relv, ip_a, ss_a, ctxb);
    psg_ln_kernel<<<NP / 4, 256, 0, stream>>>(h_psg, ctxb, lng_p, lnb_p);

    qterm_kernel<<<1, 256, 0, stream>>>(w1, b1, q_emb, qterm);
    gemm_kernel<0,2,0><<<dim3(4, NP / 64), 256, 0, stream>>>(
        h_psg, 256, w1, w1, w1, 512, qterm, qterm, qterm,
        nullptr, 256, 256, nullptr, nullptr, scores, w2, b2, nullptr);
}

// Round 6
// 717.177 us; speedup vs baseline: 1.6805x; 1.0578x over previous
//
#include <hip/hip_runtime.h>
#include <hip/hip_bf16.h>
#include <math.h>

#define DIM 256
#define NHEAD 4
#define HD 64
#define MSPLIT 4

typedef __attribute__((ext_vector_type(8))) short short8b;   // 8 bf16 (4 VGPRs)
typedef __attribute__((ext_vector_type(4))) float f32x4;

union B8 { uint4 u; short8b v; };

__device__ __forceinline__ float sigmoidf_(float x) { return 1.0f / (1.0f + __expf(-x)); }
__device__ __forceinline__ float geluf_(float x) {
    return 0.5f * x * (1.0f + erff(x * 0.70710678118654752440f));
}
__device__ __forceinline__ float wave_sum64(float v) {
    v += __shfl_xor(v, 32); v += __shfl_xor(v, 16); v += __shfl_xor(v, 8);
    v += __shfl_xor(v, 4);  v += __shfl_xor(v, 2);  v += __shfl_xor(v, 1);
    return v;
}
__device__ __forceinline__ unsigned short f2bf(float f) {   // RNE f32->bf16 bits
    union { float f; unsigned int u; } a; a.f = f;
    unsigned int u = a.u;
    unsigned int r = (u + 0x7FFFu + ((u >> 16) & 1u)) >> 16;
    return (unsigned short)r;
}
__device__ __forceinline__ unsigned int pk2bf(float lo, float hi) {
    return (unsigned int)f2bf(lo) | ((unsigned int)f2bf(hi) << 16);
}

// ---------------------------------------------------------------------------
// fp32 -> bf16 conversion passes (8 elems/thread). GELU variant for agg.
// ---------------------------------------------------------------------------
template<int DO_GELU>
__launch_bounds__(256)
__global__ void cvt_bf16_kernel(const float* __restrict__ src,
                                unsigned short* __restrict__ dst, int n8)
{
    const int i = blockIdx.x * 256 + threadIdx.x;
    if (i >= n8) return;
    float4 a = reinterpret_cast<const float4*>(src)[2 * i];
    float4 b = reinterpret_cast<const float4*>(src)[2 * i + 1];
    if (DO_GELU) {
        a.x = geluf_(a.x); a.y = geluf_(a.y); a.z = geluf_(a.z); a.w = geluf_(a.w);
        b.x = geluf_(b.x); b.y = geluf_(b.y); b.z = geluf_(b.z); b.w = geluf_(b.w);
    }
    ushort4 lo = {f2bf(a.x), f2bf(a.y), f2bf(a.z), f2bf(a.w)};
    ushort4 hi = {f2bf(b.x), f2bf(b.y), f2bf(b.z), f2bf(b.w)};
    reinterpret_cast<ushort4*>(dst)[2 * i] = lo;
    reinterpret_cast<ushort4*>(dst)[2 * i + 1] = hi;
}

// 12 weight chunks of 256x256 fp32 -> bf16 arena. blockIdx.y = chunk.
__launch_bounds__(256)
__global__ void cvt_w_kernel(const float* __restrict__ W0, const float* __restrict__ W1,
                             const float* __restrict__ W2, const float* __restrict__ W3,
                             const float* __restrict__ W4, const float* __restrict__ W5,
                             const float* __restrict__ W6, const float* __restrict__ W7,
                             const float* __restrict__ W8, const float* __restrict__ W9,
                             const float* __restrict__ W10, const float* __restrict__ W11,
                             unsigned short* __restrict__ arena)
{
    const float* s;
    switch (blockIdx.y) {
        case 0: s = W0; break;  case 1: s = W1; break;  case 2: s = W2; break;
        case 3: s = W3; break;  case 4: s = W4; break;  case 5: s = W5; break;
        case 6: s = W6; break;  case 7: s = W7; break;  case 8: s = W8; break;
        case 9: s = W9; break;  case 10: s = W10; break; default: s = W11; break;
    }
    const int i = blockIdx.x * 256 + threadIdx.x;   // 32 blocks x 256 thr x 8 = 65536
    unsigned short* dst = arena + (size_t)blockIdx.y * 65536;
    float4 a = reinterpret_cast<const float4*>(s)[2 * i];
    float4 b = reinterpret_cast<const float4*>(s)[2 * i + 1];
    ushort4 lo = {f2bf(a.x), f2bf(a.y), f2bf(a.z), f2bf(a.w)};
    ushort4 hi = {f2bf(b.x), f2bf(b.y), f2bf(b.z), f2bf(b.w)};
    reinterpret_cast<ushort4*>(dst)[2 * i] = lo;
    reinterpret_cast<ushort4*>(dst)[2 * i + 1] = hi;
}

// ---------------------------------------------------------------------------
// bf16 MFMA GEMM: C[M,Nout] = epilogue( Abf[M,256] @ Wbf^T + bias ).
// Block 256 thr = 4 waves stacked over M (BM=64); wave tile 16x64 (4 N-frags).
// Frag layouts (empirically validated by the round-4 MHA kernel):
//   A: row=lane&15, k-octet=lane>>4 (16B contiguous); B(=W row-major): col=lane&15,
//   k-octet=lane>>4 (16B contiguous); C/D: col=lane&15, row=(lane>>4)*4+reg.
// OUT_MODE 0: acc+bias; OUT_MODE 1: sigmoid-skip mix with xres.
// WF32: write fp32 C; WBF: write bf16 mirror Cbf.
// ---------------------------------------------------------------------------
template<int OUT_MODE, int WF32, int WBF>
__launch_bounds__(256)
__global__ void bgemm_kernel(const unsigned short* __restrict__ Abf,
                             const unsigned short* __restrict__ W0b,
                             const unsigned short* __restrict__ W1b,
                             const unsigned short* __restrict__ W2b,
                             const float* __restrict__ B0, const float* __restrict__ B1,
                             const float* __restrict__ B2,
                             float* __restrict__ C, int ldc,
                             unsigned short* __restrict__ Cbf, int ldcb,
                             const float* __restrict__ xres,
                             const float* __restrict__ skipv)
{
    const int t = threadIdx.x;
    const int lane = t & 63;
    const int wid = t >> 6;
    const int col16 = lane & 15;
    const int oct = lane >> 4;
    const int r0 = blockIdx.y * 64 + wid * 16;
    const int c0 = blockIdx.x * 64;
    const int widx = c0 >> 8;
    const unsigned short* W = (widx == 0) ? W0b : (widx == 1 ? W1b : W2b);
    const float* Bv = (widx == 0) ? B0 : (widx == 1 ? B1 : B2);
    const int cw = c0 & 255;

    const unsigned short* aptr = Abf + (size_t)(r0 + col16) * 256 + oct * 8;
    const unsigned short* wptr = W + (size_t)(cw + col16) * 256 + oct * 8;

    f32x4 acc0 = {0,0,0,0}, acc1 = {0,0,0,0}, acc2 = {0,0,0,0}, acc3 = {0,0,0,0};
#pragma unroll
    for (int k0 = 0; k0 < 256; k0 += 32) {
        B8 af, w0, w1, w2, w3;
        af.u = *reinterpret_cast<const uint4*>(aptr + k0);
        w0.u = *reinterpret_cast<const uint4*>(wptr + k0);
        w1.u = *reinterpret_cast<const uint4*>(wptr + k0 + 16 * 256);
        w2.u = *reinterpret_cast<const uint4*>(wptr + k0 + 32 * 256);
        w3.u = *reinterpret_cast<const uint4*>(wptr + k0 + 48 * 256);
        acc0 = __builtin_amdgcn_mfma_f32_16x16x32_bf16(af.v, w0.v, acc0, 0, 0, 0);
        acc1 = __builtin_amdgcn_mfma_f32_16x16x32_bf16(af.v, w1.v, acc1, 0, 0, 0);
        acc2 = __builtin_amdgcn_mfma_f32_16x16x32_bf16(af.v, w2.v, acc2, 0, 0, 0);
        acc3 = __builtin_amdgcn_mfma_f32_16x16x32_bf16(af.v, w3.v, acc3, 0, 0, 0);
    }

    float bias[4];
#pragma unroll
    for (int j = 0; j < 4; ++j) bias[j] = Bv[cw + j * 16 + col16];
    float sg = 0.f;
    if (OUT_MODE == 1) sg = sigmoidf_(skipv[0]);

    const float av[4][4] = {
        {acc0.x, acc0.y, acc0.z, acc0.w}, {acc1.x, acc1.y, acc1.z, acc1.w},
        {acc2.x, acc2.y, acc2.z, acc2.w}, {acc3.x, acc3.y, acc3.z, acc3.w}};
#pragma unroll
    for (int r = 0; r < 4; ++r) {
        const int row = r0 + oct * 4 + r;
#pragma unroll
        for (int j = 0; j < 4; ++j) {
            const int col = c0 + j * 16 + col16;
            float v = av[j][r] + bias[j];
            if (OUT_MODE == 1) {
                const float xv = xres[(size_t)row * ldc + col];
                v = sg * v + (1.f - sg) * xv;
            }
            if (WF32) C[(size_t)row * ldc + col] = v;
            if (WBF)  Cbf[(size_t)row * ldcb + col] = f2bf(v);
        }
    }
}

// ---------------------------------------------------------------------------
// fp32 GEMM (kept for the scoring head only).
// OUT_MODE 2: scores[r] += relu(acc+bias) . w2  (+b2 once)
// ---------------------------------------------------------------------------
template<int IN_GELU, int OUT_MODE>
__launch_bounds__(256)
__global__ void gemm_kernel(const float* __restrict__ A, int lda,
                            const float* __restrict__ W0, const float* __restrict__ W1,
                            const float* __restrict__ W2, int ldw,
                            const float* __restrict__ B0, const float* __restrict__ B1,
                            const float* __restrict__ B2,
                            float* __restrict__ C, int ldc, int Kin,
                            float* __restrict__ scores,
                            const float* __restrict__ w2v,
                            const float* __restrict__ b2v)
{
    __shared__ float As[16][68];
    __shared__ float Ws[16][68];
    const int t = threadIdx.x;
    const int r0 = blockIdx.y * 64;
    const int c0 = blockIdx.x * 64;
    const int widx = c0 >> 8;
    const float* W  = (widx == 0) ? W0 : (widx == 1 ? W1 : W2);
    const float* Bv = (widx == 0) ? B0 : (widx == 1 ? B1 : B2);
    const int cw = c0 & 255;

    const int lrow = t >> 2;
    const int lk   = (t & 3) << 2;
    const int ty = t >> 4, tx = t & 15;

    const float* Aptr = A + (size_t)(r0 + lrow) * lda + lk;
    const float* Wptr = W + (size_t)(cw + lrow) * ldw + lk;

    float acc[4][4] = {};
    for (int k0 = 0; k0 < Kin; k0 += 16) {
        float4 av = *reinterpret_cast<const float4*>(Aptr + k0);
        float4 wv = *reinterpret_cast<const float4*>(Wptr + k0);
        if (IN_GELU) {
            av.x = geluf_(av.x); av.y = geluf_(av.y);
            av.z = geluf_(av.z); av.w = geluf_(av.w);
        }
        As[lk + 0][lrow] = av.x; As[lk + 1][lrow] = av.y;
        As[lk + 2][lrow] = av.z; As[lk + 3][lrow] = av.w;
        Ws[lk + 0][lrow] = wv.x; Ws[lk + 1][lrow] = wv.y;
        Ws[lk + 2][lrow] = wv.z; Ws[lk + 3][lrow] = wv.w;
        __syncthreads();
#pragma unroll
        for (int k = 0; k < 16; ++k) {
            const float4 a = *reinterpret_cast<const float4*>(&As[k][ty << 2]);
            const float4 b = *reinterpret_cast<const float4*>(&Ws[k][tx << 2]);
            const float ar[4] = {a.x, a.y, a.z, a.w};
            const float br[4] = {b.x, b.y, b.z, b.w};
#pragma unroll
            for (int i = 0; i < 4; ++i)
#pragma unroll
                for (int j = 0; j < 4; ++j)
                    acc[i][j] = fmaf(ar[i], br[j], acc[i][j]);
        }
        __syncthreads();
    }

    float bias[4];
#pragma unroll
    for (int j = 0; j < 4; ++j) bias[j] = Bv[cw + (tx << 2) + j];

    if (OUT_MODE == 0) {
#pragma unroll
        for (int i = 0; i < 4; ++i) {
            float4 st;
            st.x = acc[i][0] + bias[0]; st.y = acc[i][1] + bias[1];
            st.z = acc[i][2] + bias[2]; st.w = acc[i][3] + bias[3];
            *reinterpret_cast<float4*>(&C[(size_t)(r0 + (ty << 2) + i) * ldc + c0 + (tx << 2)]) = st;
        }
    } else {
        float wv[4];
#pragma unroll
        for (int j = 0; j < 4; ++j) wv[j] = w2v[c0 + (tx << 2) + j];
#pragma unroll
        for (int i = 0; i < 4; ++i) {
            float p = 0.f;
#pragma unroll
            for (int j = 0; j < 4; ++j)
                p = fmaf(fmaxf(acc[i][j] + bias[j], 0.f), wv[j], p);
            if (c0 == 0 && tx == 0) p += b2v[0];
            atomicAdd(&scores[r0 + (ty << 2) + i], p);
        }
    }
}

// ---------------------------------------------------------------------------
// kt[n, h*64+e] = sum_d kin[n, h*64+d] * arel[h, d, e]      (per-head 64x64)
// ---------------------------------------------------------------------------
__launch_bounds__(256)
__global__ void rel_transform_kernel(const float* __restrict__ kin, int ldin,
                                     const float* __restrict__ arel,
                                     float* __restrict__ kout)
{
    __shared__ float Al[64][68];   // [d][e]
    __shared__ float Kl[64][65];   // [r][d]
    const int t = threadIdx.x;
    const int r0 = blockIdx.x * 64;
    const int h = blockIdx.y;
    const float* ah = arel + h * 4096;
    for (int i = t; i < 1024; i += 256) {
        const int rr = i >> 4, c4 = (i & 15) << 2;
        const float4 av = *reinterpret_cast<const float4*>(&ah[rr * 64 + c4]);
        *reinterpret_cast<float4*>(&Al[rr][c4]) = av;
        const float4 kv = *reinterpret_cast<const float4*>(&kin[(size_t)(r0 + rr) * ldin + h * 64 + c4]);
        Kl[rr][c4 + 0] = kv.x; Kl[rr][c4 + 1] = kv.y;
        Kl[rr][c4 + 2] = kv.z; Kl[rr][c4 + 3] = kv.w;
    }
    __syncthreads();
    const int r  = t & 63;
    const int e0 = (t >> 6) << 4;
    float acc[16] = {};
    for (int d = 0; d < 64; ++d) {
        const float kv = Kl[r][d];
#pragma unroll
        for (int u4 = 0; u4 < 4; ++u4) {
            const float4 a = *reinterpret_cast<const float4*>(&Al[d][e0 + (u4 << 2)]);
            acc[u4 * 4 + 0] = fmaf(kv, a.x, acc[u4 * 4 + 0]);
            acc[u4 * 4 + 1] = fmaf(kv, a.y, acc[u4 * 4 + 1]);
            acc[u4 * 4 + 2] = fmaf(kv, a.z, acc[u4 * 4 + 2]);
            acc[u4 * 4 + 3] = fmaf(kv, a.w, acc[u4 * 4 + 3]);
        }
    }
#pragma unroll
    for (int u4 = 0; u4 < 4; ++u4) {
        float4 st = {acc[u4 * 4 + 0], acc[u4 * 4 + 1], acc[u4 * 4 + 2], acc[u4 * 4 + 3]};
        *reinterpret_cast<float4*>(&kout[(size_t)(r0 + r) * 256 + h * 64 + e0 + (u4 << 2)]) = st;
    }
}

// --------------------------- CSR build -------------------------------------
__global__ void edge_count_kernel(const int* __restrict__ dst, int* __restrict__ cnt, int E)
{
    const int i = blockIdx.x * 256 + threadIdx.x;
    if (i < E) atomicAdd(&cnt[dst[i]], 1);
}

__launch_bounds__(1024)
__global__ void scan_kernel(const int* __restrict__ cnt, int* __restrict__ indptr,
                            int* __restrict__ cursor)
{
    __shared__ int sh[1024];
    const int t = threadIdx.x;
    const int4 v = *reinterpret_cast<const int4*>(&cnt[t << 2]);
    const int sum = v.x + v.y + v.z + v.w;
    sh[t] = sum;
    __syncthreads();
    for (int off = 1; off < 1024; off <<= 1) {
        int x = 0;
        if (t >= off) x = sh[t - off];
        __syncthreads();
        if (t >= off) sh[t] += x;
        __syncthreads();
    }
    int run = sh[t] - sum;
    const int base = t << 2;
    if (t == 0) indptr[0] = 0;
    cursor[base + 0] = run; run += v.x; indptr[base + 1] = run;
    cursor[base + 1] = run; run += v.y; indptr[base + 2] = run;
    cursor[base + 2] = run; run += v.z; indptr[base + 3] = run;
    cursor[base + 3] = run; run += v.w; indptr[base + 4] = run;
}

__global__ void edge_scatter_kernel(const int* __restrict__ src, const int* __restrict__ dst,
                                    int* __restrict__ cursor, int* __restrict__ ssrc, int E)
{
    const int i = blockIdx.x * 256 + threadIdx.x;
    if (i < E) {
        const int p = atomicAdd(&cursor[dst[i]], 1);
        ssrc[p] = src[i];
    }
}

// ---------------------------------------------------------------------------
// HGT edge softmax-aggregate: ONE wave per dst node, all 4 heads at once.
// ---------------------------------------------------------------------------
__launch_bounds__(256)
__global__ void hgt_attn_kernel(const float* __restrict__ qdst,   // q section base, ld=768
                                const float* __restrict__ kt,
                                const float* __restrict__ vt,
                                const float* __restrict__ prel,
                                const int* __restrict__ indptr,
                                const int* __restrict__ ssrc,
                                float* __restrict__ agg)
{
    const int n = blockIdx.x * 4 + (threadIdx.x >> 6);
    const int lane = threadIdx.x & 63;
    const int h = lane >> 4;
    const int d4 = (lane & 15) << 2;
    const float4 q = *reinterpret_cast<const float4*>(&qdst[(size_t)n * 768 + h * 64 + d4]);
    const float ps = prel[h] * 0.125f;
    const int e0 = indptr[n], e1 = indptr[n + 1];
    float m = -1e30f, s = 0.f;
    float4 acc = {0.f, 0.f, 0.f, 0.f};
    for (int e = e0; e < e1; ++e) {
        const int sr = ssrc[e];
        const float4 k = *reinterpret_cast<const float4*>(&kt[(size_t)sr * 256 + h * 64 + d4]);
        float d = q.x * k.x + q.y * k.y + q.z * k.z + q.w * k.w;
        d += __shfl_xor(d, 1); d += __shfl_xor(d, 2);
        d += __shfl_xor(d, 4); d += __shfl_xor(d, 8);
        const float logit = d * ps;
        const float mn = fmaxf(m, logit);
        const float f = __expf(m - mn);
        const float p = __expf(logit - mn);
        s = s * f + p;
        const float4 v = *reinterpret_cast<const float4*>(&vt[(size_t)sr * 256 + h * 64 + d4]);
        acc.x = acc.x * f + p * v.x;
        acc.y = acc.y * f + p * v.y;
        acc.z = acc.z * f + p * v.z;
        acc.w = acc.w * f + p * v.w;
        m = mn;
    }
    const float inv = 1.f / (s + 1e-16f);
    float4 st = {acc.x * inv, acc.y * inv, acc.z * inv, acc.w * inv};
    *reinterpret_cast<float4*>(&agg[(size_t)n * 256 + h * 64 + d4]) = st;
}

// ---------------------------------------------------------------------------
// V transpose: qkv_bf [N][768] (v section) -> vt[h*64+d][key]  (bf16)
// ---------------------------------------------------------------------------
__launch_bounds__(256)
__global__ void vtrans_kernel(const unsigned short* __restrict__ qkv_bf,
                              unsigned short* __restrict__ vt, int N)
{
    __shared__ unsigned short tile[64][66];
    const int t = threadIdx.x;
    const int k0 = blockIdx.x * 64;
    const int h = blockIdx.y;
    {
        const int key = t >> 2;
        const int d0 = (t & 3) << 4;
        const unsigned short* src = qkv_bf + (size_t)(k0 + key) * 768 + 512 + h * 64 + d0;
        const uint4 a = *reinterpret_cast<const uint4*>(src);
        const uint4 b = *reinterpret_cast<const uint4*>(src + 8);
        const unsigned int w_[8] = {a.x, a.y, a.z, a.w, b.x, b.y, b.z, b.w};
#pragma unroll
        for (int j = 0; j < 8; ++j) {
            tile[d0 + 2 * j][key]     = (unsigned short)(w_[j] & 0xffff);
            tile[d0 + 2 * j + 1][key] = (unsigned short)(w_[j] >> 16);
        }
    }
    __syncthreads();
    {
        const int d = t >> 2;
        const int kk = (t & 3) << 4;
        unsigned int o_[8];
#pragma unroll
        for (int j = 0; j < 8; ++j)
            o_[j] = (unsigned int)tile[d][kk + 2 * j] | ((unsigned int)tile[d][kk + 2 * j + 1] << 16);
        unsigned short* dstp = vt + (size_t)(h * 64 + d) * N + k0 + kk;
        uint4 s0 = {o_[0], o_[1], o_[2], o_[3]};
        uint4 s1 = {o_[4], o_[5], o_[6], o_[7]};
        *reinterpret_cast<uint4*>(dstp) = s0;
        *reinterpret_cast<uint4*>(dstp + 8) = s1;
    }
}

// ---------------------------------------------------------------------------
// MHA via bf16 MFMA, flash-decoding split-K.
// ---------------------------------------------------------------------------
__launch_bounds__(256)
__global__ void mha_mfma_kernel(const unsigned short* __restrict__ qkv_bf, // [N][768]
                                const unsigned short* __restrict__ vt_bf,  // [256][N]
                                float* __restrict__ opart,  // [MSPLIT][N][256]
                                float* __restrict__ mpart,  // [MSPLIT][NHEAD][N]
                                float* __restrict__ lpart,  // [MSPLIT][NHEAD][N]
                                int N)
{
    const int lane = threadIdx.x & 63;
    const int g = lane >> 4;
    const int q15 = lane & 15;
    const int gw = blockIdx.x * 4 + (threadIdx.x >> 6);
    const int split = gw & (MSPLIT - 1);
    const int gq = gw >> 2;
    const int h = gq >> 8;
    const int qt = gq & 255;
    const int q0 = qt * 16;
    const int kbeg = split * (N / MSPLIT);
    const int kend = kbeg + (N / MSPLIT);

    B8 qf0, qf1;
    {
        const unsigned short* qp = qkv_bf + (size_t)(q0 + q15) * 768 + h * 64 + g * 8;
        qf0.u = *reinterpret_cast<const uint4*>(qp);
        qf1.u = *reinterpret_cast<const uint4*>(qp + 32);
    }

    f32x4 o0 = {0,0,0,0}, o1 = {0,0,0,0}, o2 = {0,0,0,0}, o3 = {0,0,0,0};
    float m_run = -1e30f, l_run = 0.f;

    const unsigned short* kbase = qkv_bf + 256 + h * 64 + g * 8;
    const unsigned short* vbase = vt_bf + (size_t)(h * 64 + q15) * N + g * 8;
    const int sl0 = (((2 * g) & 3) << 4) + q15;
    const int sl1 = (((2 * g + 1) & 3) << 4) + q15;

    for (int ck = kbeg; ck < kend; ck += 32) {
        B8 k00, k01, k10, k11;
        const unsigned short* kp0 = kbase + (size_t)(ck + q15) * 768;
        const unsigned short* kp1 = kbase + (size_t)(ck + 16 + q15) * 768;
        k00.u = *reinterpret_cast<const uint4*>(kp0);
        k01.u = *reinterpret_cast<const uint4*>(kp0 + 32);
        k10.u = *reinterpret_cast<const uint4*>(kp1);
        k11.u = *reinterpret_cast<const uint4*>(kp1 + 32);
        f32x4 s0 = {0,0,0,0}, s1 = {0,0,0,0};
        s0 = __builtin_amdgcn_mfma_f32_16x16x32_bf16(k00.v, qf0.v, s0, 0, 0, 0);
        s0 = __builtin_amdgcn_mfma_f32_16x16x32_bf16(k01.v, qf1.v, s0, 0, 0, 0);
        s1 = __builtin_amdgcn_mfma_f32_16x16x32_bf16(k10.v, qf0.v, s1, 0, 0, 0);
        s1 = __builtin_amdgcn_mfma_f32_16x16x32_bf16(k11.v, qf1.v, s1, 0, 0, 0);

        float p[8];
        p[0] = s0.x * 0.125f; p[1] = s0.y * 0.125f; p[2] = s0.z * 0.125f; p[3] = s0.w * 0.125f;
        p[4] = s1.x * 0.125f; p[5] = s1.y * 0.125f; p[6] = s1.z * 0.125f; p[7] = s1.w * 0.125f;

        float mx = fmaxf(fmaxf(fmaxf(p[0], p[1]), fmaxf(p[2], p[3])),
                         fmaxf(fmaxf(p[4], p[5]), fmaxf(p[6], p[7])));
        mx = fmaxf(mx, __shfl_xor(mx, 16));
        mx = fmaxf(mx, __shfl_xor(mx, 32));
        const float mnew = fmaxf(m_run, mx);
        const float f = __expf(m_run - mnew);
        float sum = 0.f;
#pragma unroll
        for (int i = 0; i < 8; ++i) { p[i] = __expf(p[i] - mnew); sum += p[i]; }
        sum += __shfl_xor(sum, 16);
        sum += __shfl_xor(sum, 32);
        l_run = l_run * f + sum;
        m_run = mnew;
        o0 *= f; o1 *= f; o2 *= f; o3 *= f;

        const unsigned int c01a = pk2bf(p[0], p[1]), c23a = pk2bf(p[2], p[3]);
        const unsigned int c01b = pk2bf(p[4], p[5]), c23b = pk2bf(p[6], p[7]);
        uint4 pu;
        {
            unsigned int x0, x1;
            x0 = (unsigned int)__shfl((int)c01a, sl0); x1 = (unsigned int)__shfl((int)c01b, sl0);
            pu.x = (g < 2) ? x0 : x1;
            x0 = (unsigned int)__shfl((int)c23a, sl0); x1 = (unsigned int)__shfl((int)c23b, sl0);
            pu.y = (g < 2) ? x0 : x1;
            x0 = (unsigned int)__shfl((int)c01a, sl1); x1 = (unsigned int)__shfl((int)c01b, sl1);
            pu.z = (g < 2) ? x0 : x1;
            x0 = (unsigned int)__shfl((int)c23a, sl1); x1 = (unsigned int)__shfl((int)c23b, sl1);
            pu.w = (g < 2) ? x0 : x1;
        }
        B8 pb; pb.u = pu;

        const unsigned short* vp = vbase + ck;
        B8 vf;
        vf.u = *reinterpret_cast<const uint4*>(vp);
        o0 = __builtin_amdgcn_mfma_f32_16x16x32_bf16(vf.v, pb.v, o0, 0, 0, 0);
        vf.u = *reinterpret_cast<const uint4*>(vp + (size_t)16 * N);
        o1 = __builtin_amdgcn_mfma_f32_16x16x32_bf16(vf.v, pb.v, o1, 0, 0, 0);
        vf.u = *reinterpret_cast<const uint4*>(vp + (size_t)32 * N);
        o2 = __builtin_amdgcn_mfma_f32_16x16x32_bf16(vf.v, pb.v, o2, 0, 0, 0);
        vf.u = *reinterpret_cast<const uint4*>(vp + (size_t)48 * N);
        o3 = __builtin_amdgcn_mfma_f32_16x16x32_bf16(vf.v, pb.v, o3, 0, 0, 0);
    }

    float* op = opart + (size_t)split * N * 256 + (size_t)(q0 + q15) * 256 + h * 64 + 4 * g;
#pragma unroll
    for (int r = 0; r < 4; ++r) {
        op[0 * 16 + r] = o0[r];
        op[1 * 16 + r] = o1[r];
        op[2 * 16 + r] = o2[r];
        op[3 * 16 + r] = o3[r];
    }
    if (g == 0) {
        mpart[(size_t)(split * NHEAD + h) * N + q0 + q15] = m_run;
        lpart[(size_t)(split * NHEAD + h) * N + q0 + q15] = l_run;
    }
}

// Combine the MSPLIT partials -> att_o in bf16 (feeds the mha-out bgemm).
__launch_bounds__(256)
__global__ void mha_combine_kernel(const float* __restrict__ opart,
                                   const float* __restrict__ mpart,
                                   const float* __restrict__ lpart,
                                   unsigned short* __restrict__ outpb, int N)
{
    const int q = blockIdx.x;
    const int c = threadIdx.x;
    const int h = c >> 6;
    const size_t base = (size_t)q * 256 + c;
    float m[MSPLIT], l[MSPLIT];
    float M = -1e30f;
#pragma unroll
    for (int s = 0; s < MSPLIT; ++s) {
        m[s] = mpart[(size_t)(s * NHEAD + h) * N + q];
        l[s] = lpart[(size_t)(s * NHEAD + h) * N + q];
        M = fmaxf(M, m[s]);
    }
    float L = 0.f, o = 0.f;
#pragma unroll
    for (int s = 0; s < MSPLIT; ++s) {
        const float w = __expf(m[s] - M);
        L += w * l[s];
        o = fmaf(w, opart[(size_t)s * N * 256 + base], o);
    }
    outpb[base] = f2bf(o / L);
}

// ---------------------------------------------------------------------------
// h_ent = LN(0.9*h_ent + 0.1*h_glob); rel = sigmoid(h_ent . q). Wave per row.
// ---------------------------------------------------------------------------
__launch_bounds__(256)
__global__ void mix_ln_rel_kernel(float* __restrict__ he, const float* __restrict__ hg,
                                  const float* __restrict__ g, const float* __restrict__ b,
                                  const float* __restrict__ q, float* __restrict__ rel)
{
    const int row = (blockIdx.x * 256 + threadIdx.x) >> 6;
    const int lane = threadIdx.x & 63;
    const float4 a = *reinterpret_cast<const float4*>(&he[(size_t)row * 256 + (lane << 2)]);
    const float4 c = *reinterpret_cast<const float4*>(&hg[(size_t)row * 256 + (lane << 2)]);
    float4 v;
    v.x = 0.9f * a.x + 0.1f * c.x; v.y = 0.9f * a.y + 0.1f * c.y;
    v.z = 0.9f * a.z + 0.1f * c.z; v.w = 0.9f * a.w + 0.1f * c.w;
    const float mean = wave_sum64(v.x + v.y + v.z + v.w) * (1.f / 256.f);
    float4 d = {v.x - mean, v.y - mean, v.z - mean, v.w - mean};
    const float var = wave_sum64(d.x * d.x + d.y * d.y + d.z * d.z + d.w * d.w) * (1.f / 256.f);
    const float rs = rsqrtf(var + 1e-5f);
    const float4 gg = *reinterpret_cast<const float4*>(&g[lane << 2]);
    const float4 bb = *reinterpret_cast<const float4*>(&b[lane << 2]);
    float4 y = {d.x * rs * gg.x + bb.x, d.y * rs * gg.y + bb.y,
                d.z * rs * gg.z + bb.z, d.w * rs * gg.w + bb.w};
    *reinterpret_cast<float4*>(&he[(size_t)row * 256 + (lane << 2)]) = y;
    const float4 qq = *reinterpret_cast<const float4*>(&q[lane << 2]);
    const float dq = wave_sum64(y.x * qq.x + y.y * qq.y + y.z * qq.z + y.w * qq.w);
    if (lane == 0) rel[row] = sigmoidf_(dq);
}

// ctx[p] = sum_{e in seg(p)} h_ent[src]*rel[src]. Wave per (p, quarter).
__launch_bounds__(256)
__global__ void ctx_gather_kernel(const float* __restrict__ he, const float* __restrict__ rel,
                                  const int* __restrict__ indptr, const int* __restrict__ ssrc,
                                  float* __restrict__ ctx)
{
    const int gw = (blockIdx.x * 256 + threadIdx.x) >> 6;
    const int lane = threadIdx.x & 63;
    const int p = gw >> 2, qt = gw & 3;
    const int e0 = indptr[p], e1 = indptr[p + 1];
    float acc = 0.f;
    for (int e = e0; e < e1; ++e) {
        const int sr = ssrc[e];
        acc = fmaf(he[(size_t)sr * 256 + qt * 64 + lane], rel[sr], acc);
    }
    ctx[(size_t)p * 256 + qt * 64 + lane] = acc;
}

// h_psg = LN(h_psg + ctx). Wave per row.
__launch_bounds__(256)
__global__ void psg_ln_kernel(float* __restrict__ hp, const float* __restrict__ ctx,
                              const float* __restrict__ g, const float* __restrict__ b)
{
    const int row = (blockIdx.x * 256 + threadIdx.x) >> 6;
    const int lane = threadIdx.x & 63;
    const float4 a = *reinterpret_cast<const float4*>(&hp[(size_t)row * 256 + (lane << 2)]);
    const float4 c = *reinterpret_cast<const float4*>(&ctx[(size_t)row * 256 + (lane << 2)]);
    float4 v = {a.x + c.x, a.y + c.y, a.z + c.z, a.w + c.w};
    const float mean = wave_sum64(v.x + v.y + v.z + v.w) * (1.f / 256.f);
    float4 d = {v.x - mean, v.y - mean, v.z - mean, v.w - mean};
    const float var = wave_sum64(d.x * d.x + d.y * d.y + d.z * d.z + d.w * d.w) * (1.f / 256.f);
    const float rs = rsqrtf(var + 1e-5f);
    const float4 gg = *reinterpret_cast<const float4*>(&g[lane << 2]);
    const float4 bb = *reinterpret_cast<const float4*>(&b[lane << 2]);
    float4 y = {d.x * rs * gg.x + bb.x, d.y * rs * gg.y + bb.y,
                d.z * rs * gg.z + bb.z, d.w * rs * gg.w + bb.w};
    *reinterpret_cast<float4*>(&hp[(size_t)row * 256 + (lane << 2)]) = y;
}

// qterm[j] = b1[j] + w1[j, 256:512] . q
__global__ void qterm_kernel(const float* __restrict__ w1, const float* __restrict__ b1,
                             const float* __restrict__ q, float* __restrict__ qterm)
{
    __shared__ float qs[256];
    const int t = threadIdx.x;
    qs[t] = q[t];
    __syncthreads();
    float s = b1[t];
    for (int k = 0; k < 256; ++k) s = fmaf(w1[(size_t)t * 512 + 256 + k], qs[k], s);
    qterm[t] = s;
}

// ---------------------------------------------------------------------------
extern "C" void kernel_launch(void* const* d_in, const int* in_sizes, int n_in,
                              void* d_out, int out_size, void* d_ws, size_t ws_size,
                              hipStream_t stream)
{
    const float* x_ent = (const float*)d_in[0];
    const float* x_psg = (const float*)d_in[1];
    const float* q_emb = (const float*)d_in[2];
    const float* Wk_e = (const float*)d_in[3];  const float* bk_e = (const float*)d_in[4];
    const float* Wq_e = (const float*)d_in[5];  const float* bq_e = (const float*)d_in[6];
    const float* Wv_e = (const float*)d_in[7];  const float* bv_e = (const float*)d_in[8];
    const float* Wo_e = (const float*)d_in[9];  const float* bo_e = (const float*)d_in[10];
    const float* sk_e = (const float*)d_in[11];
    const float* Wk_p = (const float*)d_in[12]; const float* bk_p = (const float*)d_in[13];
    const float* Wq_p = (const float*)d_in[14]; const float* bq_p = (const float*)d_in[15];
    const float* Wv_p = (const float*)d_in[16]; const float* bv_p = (const float*)d_in[17];
    const float* Wo_p = (const float*)d_in[18]; const float* bo_p = (const float*)d_in[19];
    const float* sk_p = (const float*)d_in[20];
    const float* a_e2p = (const float*)d_in[21];
    const float* m_e2p = (const float*)d_in[22];
    const float* p_e2p = (const float*)d_in[23];
    const float* a_p2e = (const float*)d_in[24];
    const float* m_p2e = (const float*)d_in[25];
    const float* p_p2e = (const float*)d_in[26];
    const float* Wmi = (const float*)d_in[27];  const float* bmi = (const float*)d_in[28];
    const float* Wmo = (const float*)d_in[29];  const float* bmo = (const float*)d_in[30];
    const float* lng_e = (const float*)d_in[31]; const float* lnb_e = (const float*)d_in[32];
    const float* lng_p = (const float*)d_in[33]; const float* lnb_p = (const float*)d_in[34];
    const float* w1 = (const float*)d_in[35];   const float* b1 = (const float*)d_in[36];
    const float* w2 = (const float*)d_in[37];   const float* b2 = (const float*)d_in[38];
    const int* e2p_src = (const int*)d_in[39];
    const int* e2p_dst = (const int*)d_in[40];
    const int* p2e_src = (const int*)d_in[41];
    const int* p2e_dst = (const int*)d_in[42];

    const int NE = in_sizes[0] / DIM;
    const int NP = in_sizes[1] / DIM;
    const int E  = in_sizes[39];
    float* scores = (float*)d_out;

    char* wp = (char*)d_ws;
    auto alloc = [&](size_t bytes) -> void* {
        void* r = (void*)wp;
        wp += (bytes + 255) & ~(size_t)255;
        return r;
    };
    float* kqv_e = (float*)alloc((size_t)NE * 768 * 4);
    float* kqv_p = (float*)alloc((size_t)NP * 768 * 4);
    float* kt_e  = (float*)alloc((size_t)NE * 256 * 4);
    float* vt_e  = (float*)alloc((size_t)NE * 256 * 4);
    float* kt_p  = (float*)alloc((size_t)NP * 256 * 4);
    float* vt_p  = (float*)alloc((size_t)NP * 256 * 4);
    float* agg_p = (float*)alloc((size_t)NP * 256 * 4);
    float* agg_e = (float*)alloc((size_t)NE * 256 * 4);
    float* h_ent = (float*)alloc((size_t)NE * 256 * 4);
    float* h_psg = (float*)alloc((size_t)NP * 256 * 4);
    float* h_glob= (float*)alloc((size_t)NE * 256 * 4);
    float* relv  = (float*)alloc((size_t)NE * 4);
    float* ctxb  = (float*)alloc((size_t)NP * 256 * 4);
    float* qterm = (float*)alloc(256 * 4);
    unsigned short* warena  = (unsigned short*)alloc((size_t)12 * 65536 * 2);
    unsigned short* xe_bf   = (unsigned short*)alloc((size_t)NE * 256 * 2);
    unsigned short* xp_bf   = (unsigned short*)alloc((size_t)NP * 256 * 2);
    unsigned short* ge_bf   = (unsigned short*)alloc((size_t)NE * 256 * 2);
    unsigned short* gp_bf   = (unsigned short*)alloc((size_t)NP * 256 * 2);
    unsigned short* hent_bf = (unsigned short*)alloc((size_t)NE * 256 * 2);
    unsigned short* atto_bf = (unsigned short*)alloc((size_t)NE * 256 * 2);
    unsigned short* qkv_bf  = (unsigned short*)alloc((size_t)NE * 768 * 2);
    unsigned short* vt_bf   = (unsigned short*)alloc((size_t)256 * NE * 2);
    float* mpart = (float*)alloc((size_t)MSPLIT * NHEAD * NE * 4);
    float* lpart = (float*)alloc((size_t)MSPLIT * NHEAD * NE * 4);
    // opart (MSPLIT*NE*256 fp32 = 16 MB) aliases kqv_e+kqv_p (24 MB contiguous):
    // both dead once the hgt_attn dispatches complete, before mha_mfma runs.
    float* opart = kqv_e;
    int* cnt_a = (int*)alloc((size_t)NP * 4);
    int* cur_a = (int*)alloc((size_t)NP * 4);
    int* ip_a  = (int*)alloc((size_t)(NP + 1) * 4);
    int* ss_a  = (int*)alloc((size_t)E * 4);
    int* cnt_b = (int*)alloc((size_t)NE * 4);
    int* cur_b = (int*)alloc((size_t)NE * 4);
    int* ip_b  = (int*)alloc((size_t)(NE + 1) * 4);
    int* ss_b  = (int*)alloc((size_t)E * 4);

    hipMemsetAsync(cnt_a, 0, (size_t)NP * 4, stream);
    hipMemsetAsync(cnt_b, 0, (size_t)NE * 4, stream);
    hipMemsetAsync(d_out, 0, (size_t)out_size * 4, stream);

    // ---- bf16 conversions (weights + inputs) ----
    cvt_w_kernel<<<dim3(32, 12), 256, 0, stream>>>(
        Wk_e, Wq_e, Wv_e, Wo_e, Wk_p, Wq_p, Wv_p, Wo_p,
        Wmi, Wmi + 65536, Wmi + 131072, Wmo, warena);
    cvt_bf16_kernel<0><<<NE * 256 / 2048, 256, 0, stream>>>(x_ent, xe_bf, NE * 32);
    cvt_bf16_kernel<0><<<NP * 256 / 2048, 256, 0, stream>>>(x_psg, xp_bf, NP * 32);

    const int eb = (E + 255) / 256;
    edge_count_kernel<<<eb, 256, 0, stream>>>(e2p_dst, cnt_a, E);
    edge_count_kernel<<<eb, 256, 0, stream>>>(p2e_dst, cnt_b, E);
    scan_kernel<<<1, 1024, 0, stream>>>(cnt_a, ip_a, cur_a);
    scan_kernel<<<1, 1024, 0, stream>>>(cnt_b, ip_b, cur_b);
    edge_scatter_kernel<<<eb, 256, 0, stream>>>(e2p_src, e2p_dst, cur_a, ss_a, E);
    edge_scatter_kernel<<<eb, 256, 0, stream>>>(p2e_src, p2e_dst, cur_b, ss_b, E);

    // HGT k|q|v projections (bf16 MFMA)
    bgemm_kernel<0,1,0><<<dim3(12, NE / 64), 256, 0, stream>>>(
        xe_bf, warena, warena + 65536, warena + 131072, bk_e, bq_e, bv_e,
        kqv_e, 768, nullptr, 0, nullptr, nullptr);
    bgemm_kernel<0,1,0><<<dim3(12, NP / 64), 256, 0, stream>>>(
        xp_bf, warena + 4*65536, warena + 5*65536, warena + 6*65536, bk_p, bq_p, bv_p,
        kqv_p, 768, nullptr, 0, nullptr, nullptr);

    rel_transform_kernel<<<dim3(NE / 64, NHEAD), 256, 0, stream>>>(kqv_e + 0,   768, a_e2p, kt_e);
    rel_transform_kernel<<<dim3(NE / 64, NHEAD), 256, 0, stream>>>(kqv_e + 512, 768, m_e2p, vt_e);
    rel_transform_kernel<<<dim3(NP / 64, NHEAD), 256, 0, stream>>>(kqv_p + 0,   768, a_p2e, kt_p);
    rel_transform_kernel<<<dim3(NP / 64, NHEAD), 256, 0, stream>>>(kqv_p + 512, 768, m_p2e, vt_p);

    hgt_attn_kernel<<<NP / 4, 256, 0, stream>>>(kqv_p + 256, kt_e, vt_e, p_e2p, ip_a, ss_a, agg_p);
    hgt_attn_kernel<<<NE / 4, 256, 0, stream>>>(kqv_e + 256, kt_p, vt_p, p_p2e, ip_b, ss_b, agg_e);

    // HGT out: gelu+cvt, then bf16 MFMA GEMM with sigmoid-skip epilogue
    cvt_bf16_kernel<1><<<NE * 256 / 2048, 256, 0, stream>>>(agg_e, ge_bf, NE * 32);
    cvt_bf16_kernel<1><<<NP * 256 / 2048, 256, 0, stream>>>(agg_p, gp_bf, NP * 32);
    bgemm_kernel<1,1,1><<<dim3(4, NE / 64), 256, 0, stream>>>(
        ge_bf, warena + 3*65536, warena + 3*65536, warena + 3*65536, bo_e, bo_e, bo_e,
        h_ent, 256, hent_bf, 256, x_ent, sk_e);
    bgemm_kernel<1,1,0><<<dim3(4, NP / 64), 256, 0, stream>>>(
        gp_bf, warena + 7*65536, warena + 7*65536, warena + 7*65536, bo_p, bo_p, bo_p,
        h_psg, 256, nullptr, 0, x_psg, sk_p);

    // MHA: qkv projection (bf16-only out), V-transpose, split-K MFMA flash,
    // combine (bf16 out), out projection
    bgemm_kernel<0,0,1><<<dim3(12, NE / 64), 256, 0, stream>>>(
        hent_bf, warena + 8*65536, warena + 9*65536, warena + 10*65536,
        bmi, bmi + 256, bmi + 512,
        nullptr, 0, qkv_bf, 768, nullptr, nullptr);
    vtrans_kernel<<<dim3(NE / 64, NHEAD), 256, 0, stream>>>(qkv_bf, vt_bf, NE);
    mha_mfma_kernel<<<NHEAD * (NE / 16) * MSPLIT / 4, 256, 0, stream>>>(
        qkv_bf, vt_bf, opart, mpart, lpart, NE);
    mha_combine_kernel<<<NE, 256, 0, stream>>>(opart, mpart, lpart, atto_bf, NE);
    bgemm_kernel<0,1,0><<<dim3(4, NE / 64), 256, 0, stream>>>(
        atto_bf, warena + 11*65536, warena + 11*65536, warena + 11*65536, bmo, bmo, bmo,
        h_glob, 256, nullptr, 0, nullptr, nullptr);

    mix_ln_rel_kernel<<<NE / 4, 256, 0, stream>>>(h_ent, h_glob, lng_e, lnb_e, q_emb, relv);

    ctx_gather_kernel<<<NP, 256, 0, stream>>>(h_ent, relv, ip_a, ss_a, ctxb);
    psg_ln_kernel<<<NP / 4, 256, 0, stream>>>(h_psg, ctxb, lng_p, lnb_p);

    // scoring head (kept fp32)
    qterm_kernel<<<1, 256, 0, stream>>>(w1, b1, q_emb, qterm);
    gemm_kernel<0,2><<<dim3(4, NP / 64), 256, 0, stream>>>(
        h_psg, 256, w1, w1, w1, 512, qterm, qterm, qterm,
        nullptr, 256, 256, scores, w2, b2);
}